// Round 2
// baseline (2178.976 us; speedup 1.0000x reference)
//
#include <hip/hip_runtime.h>
#include <math.h>

#define N_NODES 50000
#define N_EDGES 800000
#define NADJ 4
#define FDIM 256
#define CDIM 40
#define BN_EPS 1e-5f

// ---------------------------------------------------------------- CSR build
__global__ void hist_kernel(const int* __restrict__ adj, int* __restrict__ counts) {
    int idx = blockIdx.x * blockDim.x + threadIdx.x;
    if (idx >= NADJ * N_EDGES) return;
    int a = idx / N_EDGES;
    int e = idx - a * N_EDGES;
    int dst = adj[(size_t)a * 2 * N_EDGES + N_EDGES + e];
    atomicAdd(&counts[a * N_NODES + dst], 1);
}

// one block per adjacency (256 threads); counts live in `cursor`, rewritten
// in-place with exclusive offsets; row_start[a][0..N] gets the scan.
__global__ __launch_bounds__(256) void scan_kernel(int* __restrict__ cursor,
                                                   int* __restrict__ row_start) {
    int a = blockIdx.x;
    __shared__ int wsum[4];
    __shared__ int carry;
    int lane = threadIdx.x & 63;
    int wid = threadIdx.x >> 6;   // 0..3
    if (threadIdx.x == 0) { carry = 0; row_start[a * (N_NODES + 1)] = 0; }
    __syncthreads();
    for (int base = 0; base < N_NODES; base += 256) {
        int i = base + threadIdx.x;
        int v = (i < N_NODES) ? cursor[a * N_NODES + i] : 0;
        int x = v;
        #pragma unroll
        for (int off = 1; off < 64; off <<= 1) {
            int t = __shfl_up(x, off);
            if (lane >= off) x += t;
        }
        if (lane == 63) wsum[wid] = x;
        __syncthreads();
        if (threadIdx.x == 0) {
            int s = 0;
            #pragma unroll
            for (int w = 0; w < 4; ++w) { int t = wsum[w]; wsum[w] = s; s = t + s; }
        }
        __syncthreads();
        int inc = x + wsum[wid] + carry;   // inclusive global prefix
        if (i < N_NODES) {
            row_start[a * (N_NODES + 1) + i + 1] = inc;
            cursor[a * N_NODES + i] = inc - v;   // exclusive
        }
        __syncthreads();
        if (threadIdx.x == 255) carry = inc;
        __syncthreads();
    }
}

__global__ void scatter_kernel(const int* __restrict__ adj, int* __restrict__ cursor,
                               int* __restrict__ esrc) {
    int idx = blockIdx.x * blockDim.x + threadIdx.x;
    if (idx >= NADJ * N_EDGES) return;
    int a = idx / N_EDGES;
    int e = idx - a * N_EDGES;
    int src = adj[(size_t)a * 2 * N_EDGES + e];
    int dst = adj[(size_t)a * 2 * N_EDGES + N_EDGES + e];
    int pos = atomicAdd(&cursor[a * N_NODES + dst], 1);
    esrc[(size_t)a * N_EDGES + pos] = src;
}

__global__ void dinv_kernel(const int* __restrict__ row_start, float* __restrict__ dinv) {
    int idx = blockIdx.x * blockDim.x + threadIdx.x;
    if (idx >= NADJ * N_NODES) return;
    int a = idx / N_NODES;
    int n = idx - a * N_NODES;
    int d = row_start[a * (N_NODES + 1) + n + 1] - row_start[a * (N_NODES + 1) + n] + 1;
    dinv[idx] = rsqrtf((float)d);
}

// ------------------------------------------------------------- aggregation
// g[n] = sum_{e: dst=n} dinv[src]*dinv[n]*xin[src] + dinv[n]^2 * xin[n]
__global__ void agg_kernel(const float* __restrict__ xin, const int* __restrict__ row_start,
                           const int* __restrict__ esrc, const float* __restrict__ dinv,
                           float* __restrict__ gout) {
    int n = blockIdx.x;
    int f = threadIdx.x;   // 256 threads = 256 features
    int beg = row_start[n];
    int end = row_start[n + 1];
    float dn = dinv[n];
    float acc = dn * dn * xin[(size_t)n * FDIM + f];
    for (int p = beg; p < end; ++p) {
        int s = esrc[p];
        float w = dn * dinv[s];
        acc += w * xin[(size_t)s * FDIM + f];
    }
    gout[(size_t)n * FDIM + f] = acc;
}

// ------------------------------------------------ branch GEMM (+ epilogue)
// out = epilogue(A[N,256] @ W[256,256] + bias)
// mode 0: relu(y+b)*mask[branch] ; mode 1: relu(bn1(y+b)) ; mode 2: relu(bn2(y+b))*mask[3]
__global__ __launch_bounds__(256) void gemm_act(
        const float* __restrict__ A, const float* __restrict__ W,
        const float* __restrict__ bias,
        const float* __restrict__ gamma, const float* __restrict__ beta,
        const float* __restrict__ mean, const float* __restrict__ var,
        const float* __restrict__ att, int branch, int mode,
        float* __restrict__ out) {
    __shared__ float As[64][33];
    __shared__ float Bs[32][64];
    int tid = threadIdx.x;
    int row0 = blockIdx.x * 64;
    int n0 = blockIdx.y * 64;
    int tm = tid >> 4;      // 0..15
    int tn = tid & 15;      // 0..15
    float acc[4][4] = {};
    int ar = tid >> 3;           // 0..31
    int ac = (tid & 7) * 4;      // 0..28
    int bk = tid >> 4;           // 0..15
    int bc = (tid & 15) * 4;     // 0..60
    for (int k0 = 0; k0 < 256; k0 += 32) {
        #pragma unroll
        for (int rr = 0; rr < 2; ++rr) {
            int row = row0 + ar + rr * 32;
            int rc = row < N_NODES ? row : N_NODES - 1;
            float4 v = *reinterpret_cast<const float4*>(&A[(size_t)rc * 256 + k0 + ac]);
            As[ar + rr * 32][ac + 0] = v.x;
            As[ar + rr * 32][ac + 1] = v.y;
            As[ar + rr * 32][ac + 2] = v.z;
            As[ar + rr * 32][ac + 3] = v.w;
        }
        #pragma unroll
        for (int rr = 0; rr < 2; ++rr) {
            float4 v = *reinterpret_cast<const float4*>(&W[(size_t)(k0 + bk + rr * 16) * 256 + n0 + bc]);
            *reinterpret_cast<float4*>(&Bs[bk + rr * 16][bc]) = v;
        }
        __syncthreads();
        #pragma unroll
        for (int kk = 0; kk < 32; ++kk) {
            float av[4];
            #pragma unroll
            for (int i = 0; i < 4; ++i) av[i] = As[tm * 4 + i][kk];
            float4 b4 = *reinterpret_cast<const float4*>(&Bs[kk][tn * 4]);
            float bv[4] = {b4.x, b4.y, b4.z, b4.w};
            #pragma unroll
            for (int i = 0; i < 4; ++i)
                #pragma unroll
                for (int j = 0; j < 4; ++j)
                    acc[i][j] += av[i] * bv[j];
        }
        __syncthreads();
    }
    // epilogue
    float m4 = 1.0f;
    if (mode == 0 || mode == 2) {
        float a0 = att[0], a1 = att[1], a2 = att[2], a3 = att[3];
        float mx = fmaxf(fmaxf(a0, a1), fmaxf(a2, a3));
        float e0 = expf(a0 - mx), e1 = expf(a1 - mx), e2 = expf(a2 - mx), e3 = expf(a3 - mx);
        float s = e0 + e1 + e2 + e3;
        float sel = (branch == 0) ? e0 : (branch == 1) ? e1 : (branch == 2) ? e2 : e3;
        m4 = sel / s;
    }
    #pragma unroll
    for (int i = 0; i < 4; ++i) {
        int row = row0 + tm * 4 + i;
        if (row >= N_NODES) continue;
        #pragma unroll
        for (int j = 0; j < 4; ++j) {
            int col = n0 + tn * 4 + j;
            float y = acc[i][j] + bias[col];
            if (mode >= 1)
                y = (y - mean[col]) * rsqrtf(var[col] + BN_EPS) * gamma[col] + beta[col];
            y = fmaxf(y, 0.0f) * m4;
            out[(size_t)row * 256 + col] = y;
        }
    }
}

// -------------------------------------- classifier partial GEMM into logits
// logits[N,40] (+)= A[N,256] @ Wc[256,40]  (+ b_cls when accumulate==0)
__global__ __launch_bounds__(256) void gemm_cls(
        const float* __restrict__ A, const float* __restrict__ Wc,
        const float* __restrict__ bcls, float* __restrict__ logits, int accumulate) {
    __shared__ float As[64][33];
    __shared__ float Bs[32][40];
    int tid = threadIdx.x;
    int row0 = blockIdx.x * 64;
    int tm = tid >> 3;      // 0..31 -> 2 rows each
    int tn = tid & 7;       // 0..7  -> 5 cols each
    float acc[2][5] = {};
    int ar = tid >> 3;
    int ac = (tid & 7) * 4;
    for (int k0 = 0; k0 < 256; k0 += 32) {
        #pragma unroll
        for (int rr = 0; rr < 2; ++rr) {
            int row = row0 + ar + rr * 32;
            int rc = row < N_NODES ? row : N_NODES - 1;
            float4 v = *reinterpret_cast<const float4*>(&A[(size_t)rc * 256 + k0 + ac]);
            As[ar + rr * 32][ac + 0] = v.x;
            As[ar + rr * 32][ac + 1] = v.y;
            As[ar + rr * 32][ac + 2] = v.z;
            As[ar + rr * 32][ac + 3] = v.w;
        }
        for (int idx = tid; idx < 32 * 40; idx += 256) {
            int kk = idx / 40;
            int c = idx - kk * 40;
            Bs[kk][c] = Wc[(size_t)(k0 + kk) * 40 + c];
        }
        __syncthreads();
        #pragma unroll
        for (int kk = 0; kk < 32; ++kk) {
            float a0 = As[tm * 2 + 0][kk];
            float a1 = As[tm * 2 + 1][kk];
            float bv[5];
            #pragma unroll
            for (int j = 0; j < 5; ++j) bv[j] = Bs[kk][tn * 5 + j];
            #pragma unroll
            for (int j = 0; j < 5; ++j) {
                acc[0][j] += a0 * bv[j];
                acc[1][j] += a1 * bv[j];
            }
        }
        __syncthreads();
    }
    #pragma unroll
    for (int i = 0; i < 2; ++i) {
        int row = row0 + tm * 2 + i;
        if (row >= N_NODES) continue;
        #pragma unroll
        for (int j = 0; j < 5; ++j) {
            int c = tn * 5 + j;
            if (accumulate)
                logits[(size_t)row * CDIM + c] += acc[i][j];
            else
                logits[(size_t)row * CDIM + c] = acc[i][j] + bcls[c];
        }
    }
}

// ----------------------------------------------------------- log_softmax
__global__ void lsm_kernel(const float* __restrict__ logits, float* __restrict__ out) {
    int n = blockIdx.x * 4 + (threadIdx.x >> 6);
    int lane = threadIdx.x & 63;
    if (blockIdx.x == 0 && threadIdx.x == 0)
        out[(size_t)N_NODES * CDIM] = 0.0f;   // trailing scalar output
    if (n >= N_NODES) return;
    float v = (lane < CDIM) ? logits[(size_t)n * CDIM + lane] : -INFINITY;
    float m = v;
    #pragma unroll
    for (int off = 32; off >= 1; off >>= 1) m = fmaxf(m, __shfl_xor(m, off));
    float ex = (lane < CDIM) ? expf(v - m) : 0.0f;
    float s = ex;
    #pragma unroll
    for (int off = 32; off >= 1; off >>= 1) s += __shfl_xor(s, off);
    float ls = logf(s) + m;
    if (lane < CDIM) out[(size_t)n * CDIM + lane] = v - ls;
}

// ------------------------------------------------------------------ launch
extern "C" void kernel_launch(void* const* d_in, const int* in_sizes, int n_in,
                              void* d_out, int out_size, void* d_ws, size_t ws_size,
                              hipStream_t stream) {
    const float* x        = (const float*)d_in[0];
    const int*   adj      = (const int*)d_in[1];
    const float* W_convs  = (const float*)d_in[2];
    const float* b_convs  = (const float*)d_in[3];
    const float* W_extra  = (const float*)d_in[4];
    const float* b_extra  = (const float*)d_in[5];
    const float* bn1_g    = (const float*)d_in[6];
    const float* bn1_b    = (const float*)d_in[7];
    const float* bn1_m    = (const float*)d_in[8];
    const float* bn1_v    = (const float*)d_in[9];
    const float* W_extra2 = (const float*)d_in[10];
    const float* b_extra2 = (const float*)d_in[11];
    const float* bn2_g    = (const float*)d_in[12];
    const float* bn2_b    = (const float*)d_in[13];
    const float* bn2_m    = (const float*)d_in[14];
    const float* bn2_v    = (const float*)d_in[15];
    const float* att      = (const float*)d_in[16];
    const float* W_cls    = (const float*)d_in[17];
    const float* b_cls    = (const float*)d_in[18];
    float* out = (float*)d_out;

    char* base = (char*)d_ws;
    size_t off = 0;
    auto carve = [&](size_t bytes) -> char* {
        char* p = base + off;
        off = (off + bytes + 255) & ~(size_t)255;
        return p;
    };
    int*   row_start = (int*)carve(sizeof(int) * NADJ * (N_NODES + 1));
    int*   cursor    = (int*)carve(sizeof(int) * NADJ * N_NODES);
    int*   esrc      = (int*)carve(sizeof(int) * (size_t)NADJ * N_EDGES);
    float* dinv      = (float*)carve(sizeof(float) * NADJ * N_NODES);
    float* g         = (float*)carve(sizeof(float) * (size_t)N_NODES * FDIM);
    float* act       = (float*)carve(sizeof(float) * (size_t)N_NODES * FDIM);
    float* e1b       = (float*)carve(sizeof(float) * (size_t)N_NODES * FDIM);
    float* logits    = (float*)carve(sizeof(float) * (size_t)N_NODES * CDIM);

    hipMemsetAsync(cursor, 0, sizeof(int) * NADJ * N_NODES, stream);
    hist_kernel<<<(NADJ * N_EDGES + 255) / 256, 256, 0, stream>>>(adj, cursor);
    scan_kernel<<<NADJ, 256, 0, stream>>>(cursor, row_start);
    scatter_kernel<<<(NADJ * N_EDGES + 255) / 256, 256, 0, stream>>>(adj, cursor, esrc);
    dinv_kernel<<<(NADJ * N_NODES + 255) / 256, 256, 0, stream>>>(row_start, dinv);

    dim3 gemm_grid((N_NODES + 63) / 64, FDIM / 64);
    int cls_grid = (N_NODES + 63) / 64;

    // jump branches: z_i = relu(agg_{i+1}(x@W_i) + b_i) * mask[i]
    for (int i = 0; i < 3; ++i) {
        int a = i + 1;
        agg_kernel<<<N_NODES, 256, 0, stream>>>(x, row_start + a * (N_NODES + 1),
                                                esrc + (size_t)a * N_EDGES,
                                                dinv + a * N_NODES, g);
        gemm_act<<<gemm_grid, 256, 0, stream>>>(g, W_convs + (size_t)i * FDIM * FDIM,
                                                b_convs + i * FDIM,
                                                nullptr, nullptr, nullptr, nullptr,
                                                att, i, 0, act);
        gemm_cls<<<cls_grid, 256, 0, stream>>>(act, W_cls + (size_t)i * FDIM * CDIM,
                                               b_cls, logits, i == 0 ? 0 : 1);
    }
    // extra branch (two GCN layers on adj[0])
    agg_kernel<<<N_NODES, 256, 0, stream>>>(x, row_start, esrc, dinv, g);
    gemm_act<<<gemm_grid, 256, 0, stream>>>(g, W_extra, b_extra,
                                            bn1_g, bn1_b, bn1_m, bn1_v, att, 3, 1, e1b);
    agg_kernel<<<N_NODES, 256, 0, stream>>>(e1b, row_start, esrc, dinv, g);
    gemm_act<<<gemm_grid, 256, 0, stream>>>(g, W_extra2, b_extra2,
                                            bn2_g, bn2_b, bn2_m, bn2_v, att, 3, 2, act);
    gemm_cls<<<cls_grid, 256, 0, stream>>>(act, W_cls + (size_t)3 * FDIM * CDIM,
                                           b_cls, logits, 1);

    lsm_kernel<<<(N_NODES + 3) / 4, 256, 0, stream>>>(logits, out);
}

// Round 4
// 2032.747 us; speedup vs baseline: 1.0719x; 1.0719x over previous
//
#include <hip/hip_runtime.h>
#include <math.h>

#define N_NODES 50000
#define N_EDGES 800000
#define NADJ 4
#define FDIM 256
#define CDIM 40
#define BN_EPS 1e-5f
#define NBUCK 64
#define BUCK_SZ 782   // ceil(50000/64)

typedef __attribute__((ext_vector_type(8))) short short8;
typedef __attribute__((ext_vector_type(4))) float f32x4;

__device__ __forceinline__ float bf2f(unsigned short u) {
    union { unsigned int i; float f; } c; c.i = ((unsigned int)u) << 16; return c.f;
}
__device__ __forceinline__ unsigned short f2bf(float f) {
    union { float f; unsigned int i; } c; c.f = f;
    unsigned int u = c.i;
    u += 0x7fffu + ((u >> 16) & 1u);
    return (unsigned short)(u >> 16);
}

// ---------------------------------------------------------------- CSR build
__global__ void hist_kernel(const int* __restrict__ adj, int* __restrict__ counts) {
    int idx = blockIdx.x * blockDim.x + threadIdx.x;
    if (idx >= NADJ * N_EDGES) return;
    int a = idx / N_EDGES;
    int e = idx - a * N_EDGES;
    int dst = adj[(size_t)a * 2 * N_EDGES + N_EDGES + e];
    atomicAdd(&counts[a * N_NODES + dst], 1);
}

__global__ __launch_bounds__(256) void scan_kernel(const int* __restrict__ counts,
                                                   int* __restrict__ row_start) {
    int a = blockIdx.x;
    __shared__ int wsum[4];
    __shared__ int carry;
    int lane = threadIdx.x & 63;
    int wid = threadIdx.x >> 6;   // 0..3
    if (threadIdx.x == 0) { carry = 0; row_start[a * (N_NODES + 1)] = 0; }
    __syncthreads();
    for (int base = 0; base < N_NODES; base += 256) {
        int i = base + threadIdx.x;
        int v = (i < N_NODES) ? counts[a * N_NODES + i] : 0;
        int x = v;
        #pragma unroll
        for (int off = 1; off < 64; off <<= 1) {
            int t = __shfl_up(x, off);
            if (lane >= off) x += t;
        }
        if (lane == 63) wsum[wid] = x;
        __syncthreads();
        if (threadIdx.x == 0) {
            int s = 0;
            #pragma unroll
            for (int w = 0; w < 4; ++w) { int t = wsum[w]; wsum[w] = s; s = t + s; }
        }
        __syncthreads();
        int inc = x + wsum[wid] + carry;   // inclusive global prefix
        if (i < N_NODES) row_start[a * (N_NODES + 1) + i + 1] = inc;
        __syncthreads();
        if (threadIdx.x == 255) carry = inc;
        __syncthreads();
    }
}

// dst-range-owning scatter: block (a, b) owns dst in [b*BUCK_SZ, ...+BUCK_SZ);
// scans all edges of adjacency a, writes only its own dense CSR region.
__global__ __launch_bounds__(256) void range_scatter_kernel(
        const int* __restrict__ adj, const int* __restrict__ row_start,
        unsigned short* __restrict__ esrc) {
    __shared__ int cur[BUCK_SZ];
    int a = blockIdx.x >> 6;
    int b = blockIdx.x & 63;
    int lo = b * BUCK_SZ;
    int hi = lo + BUCK_SZ; if (hi > N_NODES) hi = N_NODES;
    int nloc = hi - lo;
    for (int i = threadIdx.x; i < nloc; i += 256)
        cur[i] = row_start[a * (N_NODES + 1) + lo + i];
    __syncthreads();
    const int* dsts = adj + (size_t)a * 2 * N_EDGES + N_EDGES;
    const int* srcs = adj + (size_t)a * 2 * N_EDGES;
    unsigned short* eout = esrc + (size_t)a * N_EDGES;
    for (int e4 = threadIdx.x; e4 < N_EDGES / 4; e4 += 256) {
        int4 d = reinterpret_cast<const int4*>(dsts)[e4];
        int e = e4 * 4;
        if (d.x >= lo && d.x < hi) { int p = atomicAdd(&cur[d.x - lo], 1); eout[p] = (unsigned short)srcs[e + 0]; }
        if (d.y >= lo && d.y < hi) { int p = atomicAdd(&cur[d.y - lo], 1); eout[p] = (unsigned short)srcs[e + 1]; }
        if (d.z >= lo && d.z < hi) { int p = atomicAdd(&cur[d.z - lo], 1); eout[p] = (unsigned short)srcs[e + 2]; }
        if (d.w >= lo && d.w < hi) { int p = atomicAdd(&cur[d.w - lo], 1); eout[p] = (unsigned short)srcs[e + 3]; }
    }
}

__global__ void dinv_kernel(const int* __restrict__ row_start, float* __restrict__ dinv) {
    int idx = blockIdx.x * blockDim.x + threadIdx.x;
    if (idx >= NADJ * N_NODES) return;
    int a = idx / N_NODES;
    int n = idx - a * N_NODES;
    int d = row_start[a * (N_NODES + 1) + n + 1] - row_start[a * (N_NODES + 1) + n] + 1;
    dinv[idx] = rsqrtf((float)d);
}

// ------------------------------------------------------------- conversions
// x [N,256] fp32 -> xb bf16
__global__ void convx_kernel(const float* __restrict__ x, unsigned short* __restrict__ xb) {
    int i = blockIdx.x * blockDim.x + threadIdx.x;   // one float4 per thread
    if (i >= N_NODES * FDIM / 4) return;
    float4 v = *reinterpret_cast<const float4*>(&x[(size_t)i * 4]);
    ushort4 o;
    o.x = f2bf(v.x); o.y = f2bf(v.y); o.z = f2bf(v.z); o.w = f2bf(v.w);
    *reinterpret_cast<ushort4*>(&xb[(size_t)i * 4]) = o;
}

// weights -> transposed bf16.  Wt[5][256][256]: Wt[w][n][k] = Wsrc[w][k][n]
// Wct[4][48][256]: Wct[b][c][k] = c<40 ? W_cls[(b*256+k)*40+c] : 0
__global__ void convw_kernel(const float* __restrict__ W_convs, const float* __restrict__ W_extra,
                             const float* __restrict__ W_extra2, const float* __restrict__ W_cls,
                             unsigned short* __restrict__ Wt, unsigned short* __restrict__ Wct) {
    int idx = blockIdx.x * blockDim.x + threadIdx.x;
    const int NSQ = 5 * 65536;
    if (idx < NSQ) {
        int w = idx >> 16;
        int rem = idx & 65535;
        int n = rem >> 8;
        int k = rem & 255;
        const float* src = (w < 3) ? (W_convs + (size_t)w * 65536)
                                   : ((w == 3) ? W_extra : W_extra2);
        Wt[idx] = f2bf(src[(size_t)k * 256 + n]);
    } else if (idx < NSQ + 4 * 48 * 256) {
        int rem = idx - NSQ;
        int b = rem / (48 * 256);
        int r2 = rem - b * (48 * 256);
        int c = r2 >> 8;
        int k = r2 & 255;
        float v = (c < CDIM) ? W_cls[((size_t)b * 256 + k) * CDIM + c] : 0.0f;
        Wct[rem] = f2bf(v);
    }
}

// ------------------------------------------------------------- aggregation
// one wave per node; lane handles 4 features (8B ushort4 loads)
// g[n] = sum_{e: dst=n} dinv[src]*dinv[n]*xin[src] + dinv[n]^2 * xin[n]
__global__ __launch_bounds__(256) void agg_kernel(
        const unsigned short* __restrict__ xb, const int* __restrict__ row_start,
        const unsigned short* __restrict__ esrc, const float* __restrict__ dinv,
        unsigned short* __restrict__ gout) {
    int lane = threadIdx.x & 63;
    int n = blockIdx.x * 4 + (threadIdx.x >> 6);
    if (n >= N_NODES) return;
    int beg = row_start[n];
    int end = row_start[n + 1];
    float dn = dinv[n];
    size_t fo = (size_t)lane * 4;
    ushort4 sv = *reinterpret_cast<const ushort4*>(&xb[(size_t)n * FDIM + fo]);
    float ws = dn * dn;
    float a0 = ws * bf2f(sv.x), a1 = ws * bf2f(sv.y), a2 = ws * bf2f(sv.z), a3 = ws * bf2f(sv.w);
    for (int p = beg; p < end; ++p) {
        int s = (int)esrc[p];
        float w = dn * dinv[s];
        ushort4 v = *reinterpret_cast<const ushort4*>(&xb[(size_t)s * FDIM + fo]);
        a0 += w * bf2f(v.x); a1 += w * bf2f(v.y); a2 += w * bf2f(v.z); a3 += w * bf2f(v.w);
    }
    ushort4 o;
    o.x = f2bf(a0); o.y = f2bf(a1); o.z = f2bf(a2); o.w = f2bf(a3);
    *reinterpret_cast<ushort4*>(&gout[(size_t)n * FDIM + fo]) = o;
}

// ------------------------------------------------ branch GEMM via MFMA bf16
// out = epilogue(A[N,256] @ W[256,256] + bias), A bf16, Wt = W^T bf16 [n][k]
// block: 256 thr = 4 waves; wave w -> cols [w*64, w*64+64); block -> 16 rows
// mode 0: relu(y+b)*mask[branch]; 1: relu(bn1(y+b)); 2: relu(bn2(y+b))*mask[3]
__global__ __launch_bounds__(256) void gemm_act_mfma(
        const unsigned short* __restrict__ A, const unsigned short* __restrict__ Wt,
        const float* __restrict__ bias,
        const float* __restrict__ gamma, const float* __restrict__ beta,
        const float* __restrict__ mean, const float* __restrict__ var,
        const float* __restrict__ att, int branch, int mode,
        unsigned short* __restrict__ outb) {
    int lane = threadIdx.x & 63;
    int wv = threadIdx.x >> 6;
    int row0 = blockIdx.x * 16;          // 3125 blocks * 16 = 50000 exactly
    int n0 = wv * 64;
    int r = lane & 15;
    int g = lane >> 4;
    f32x4 acc[4] = {{0.f,0.f,0.f,0.f},{0.f,0.f,0.f,0.f},{0.f,0.f,0.f,0.f},{0.f,0.f,0.f,0.f}};
    const unsigned short* arow = A + (size_t)(row0 + r) * 256 + g * 8;
    #pragma unroll
    for (int t = 0; t < 8; ++t) {
        short8 a = *reinterpret_cast<const short8*>(arow + t * 32);
        #pragma unroll
        for (int f = 0; f < 4; ++f) {
            short8 b = *reinterpret_cast<const short8*>(
                Wt + (size_t)(n0 + f * 16 + r) * 256 + t * 32 + g * 8);
            acc[f] = __builtin_amdgcn_mfma_f32_16x16x32_bf16(a, b, acc[f], 0, 0, 0);
        }
    }
    float m4 = 1.0f;
    if (mode == 0 || mode == 2) {
        float c0 = att[0], c1 = att[1], c2 = att[2], c3 = att[3];
        float mx = fmaxf(fmaxf(c0, c1), fmaxf(c2, c3));
        float e0 = expf(c0 - mx), e1 = expf(c1 - mx), e2 = expf(c2 - mx), e3 = expf(c3 - mx);
        float s = e0 + e1 + e2 + e3;
        float sel = (branch == 0) ? e0 : (branch == 1) ? e1 : (branch == 2) ? e2 : e3;
        m4 = sel / s;
    }
    #pragma unroll
    for (int f = 0; f < 4; ++f) {
        int col = n0 + f * 16 + r;
        float bi = bias[col];
        float mu = 0.f, rs = 1.f, ga = 1.f, be = 0.f;
        if (mode >= 1) {
            mu = mean[col]; rs = rsqrtf(var[col] + BN_EPS); ga = gamma[col]; be = beta[col];
        }
        #pragma unroll
        for (int j = 0; j < 4; ++j) {
            int row = row0 + g * 4 + j;
            float y = acc[f][j] + bi;
            if (mode >= 1) y = (y - mu) * rs * ga + be;
            y = fmaxf(y, 0.0f) * m4;
            outb[(size_t)row * 256 + col] = f2bf(y);
        }
    }
}

// -------------------------------------- classifier partial GEMM into logits
// logits[N,40] (+)= A[N,256] @ Wc[256,40]; Wct [48][256] bf16 (cols 40..47 zero)
// block: 4 waves, wave w -> rows [blk*64 + w*16, +16), cols 0..47
__global__ __launch_bounds__(256) void gemm_cls_mfma(
        const unsigned short* __restrict__ A, const unsigned short* __restrict__ Wct,
        const float* __restrict__ bcls, float* __restrict__ logits, int first) {
    int lane = threadIdx.x & 63;
    int wv = threadIdx.x >> 6;
    int row0 = blockIdx.x * 64 + wv * 16;
    int r = lane & 15;
    int g = lane >> 4;
    f32x4 acc[3] = {{0.f,0.f,0.f,0.f},{0.f,0.f,0.f,0.f},{0.f,0.f,0.f,0.f}};
    int ar = row0 + r; if (ar > N_NODES - 1) ar = N_NODES - 1;
    const unsigned short* arow = A + (size_t)ar * 256 + g * 8;
    #pragma unroll
    for (int t = 0; t < 8; ++t) {
        short8 a = *reinterpret_cast<const short8*>(arow + t * 32);
        #pragma unroll
        for (int f = 0; f < 3; ++f) {
            short8 b = *reinterpret_cast<const short8*>(
                Wct + (size_t)(f * 16 + r) * 256 + t * 32 + g * 8);
            acc[f] = __builtin_amdgcn_mfma_f32_16x16x32_bf16(a, b, acc[f], 0, 0, 0);
        }
    }
    #pragma unroll
    for (int f = 0; f < 3; ++f) {
        int col = f * 16 + r;
        if (col >= CDIM) continue;
        float bi = bcls[col];
        #pragma unroll
        for (int j = 0; j < 4; ++j) {
            int row = row0 + g * 4 + j;
            if (row >= N_NODES) continue;
            float v = acc[f][j];
            if (first) logits[(size_t)row * CDIM + col] = v + bi;
            else       logits[(size_t)row * CDIM + col] += v;
        }
    }
}

// ----------------------------------------------------------- log_softmax
__global__ void lsm_kernel(const float* __restrict__ logits, float* __restrict__ out) {
    int n = blockIdx.x * 4 + (threadIdx.x >> 6);
    int lane = threadIdx.x & 63;
    if (blockIdx.x == 0 && threadIdx.x == 0)
        out[(size_t)N_NODES * CDIM] = 0.0f;   // trailing scalar output
    if (n >= N_NODES) return;
    float v = (lane < CDIM) ? logits[(size_t)n * CDIM + lane] : -INFINITY;
    float m = v;
    #pragma unroll
    for (int off = 32; off >= 1; off >>= 1) m = fmaxf(m, __shfl_xor(m, off));
    float ex = (lane < CDIM) ? expf(v - m) : 0.0f;
    float s = ex;
    #pragma unroll
    for (int off = 32; off >= 1; off >>= 1) s += __shfl_xor(s, off);
    float ls = logf(s) + m;
    if (lane < CDIM) out[(size_t)n * CDIM + lane] = v - ls;
}

// ------------------------------------------------------------------ launch
extern "C" void kernel_launch(void* const* d_in, const int* in_sizes, int n_in,
                              void* d_out, int out_size, void* d_ws, size_t ws_size,
                              hipStream_t stream) {
    const float* x        = (const float*)d_in[0];
    const int*   adj      = (const int*)d_in[1];
    const float* W_convs  = (const float*)d_in[2];
    const float* b_convs  = (const float*)d_in[3];
    const float* W_extra  = (const float*)d_in[4];
    const float* b_extra  = (const float*)d_in[5];
    const float* bn1_g    = (const float*)d_in[6];
    const float* bn1_b    = (const float*)d_in[7];
    const float* bn1_m    = (const float*)d_in[8];
    const float* bn1_v    = (const float*)d_in[9];
    const float* W_extra2 = (const float*)d_in[10];
    const float* b_extra2 = (const float*)d_in[11];
    const float* bn2_g    = (const float*)d_in[12];
    const float* bn2_b    = (const float*)d_in[13];
    const float* bn2_m    = (const float*)d_in[14];
    const float* bn2_v    = (const float*)d_in[15];
    const float* att      = (const float*)d_in[16];
    const float* W_cls    = (const float*)d_in[17];
    const float* b_cls    = (const float*)d_in[18];
    float* out = (float*)d_out;

    char* base = (char*)d_ws;
    size_t off = 0;
    auto carve = [&](size_t bytes) -> char* {
        char* p = base + off;
        off = (off + bytes + 255) & ~(size_t)255;
        return p;
    };
    int*   row_start = (int*)carve(sizeof(int) * NADJ * (N_NODES + 1));
    int*   counts    = (int*)carve(sizeof(int) * NADJ * N_NODES);
    unsigned short* esrc = (unsigned short*)carve(sizeof(short) * (size_t)NADJ * N_EDGES);
    float* dinv      = (float*)carve(sizeof(float) * NADJ * N_NODES);
    unsigned short* xb   = (unsigned short*)carve(sizeof(short) * (size_t)N_NODES * FDIM);
    unsigned short* gb   = (unsigned short*)carve(sizeof(short) * (size_t)N_NODES * FDIM);
    unsigned short* actb = (unsigned short*)carve(sizeof(short) * (size_t)N_NODES * FDIM);
    unsigned short* e1b  = (unsigned short*)carve(sizeof(short) * (size_t)N_NODES * FDIM);
    unsigned short* Wt   = (unsigned short*)carve(sizeof(short) * 5 * 65536);
    unsigned short* Wct  = (unsigned short*)carve(sizeof(short) * 4 * 48 * 256);
    float* logits    = (float*)carve(sizeof(float) * (size_t)N_NODES * CDIM);

    hipMemsetAsync(counts, 0, sizeof(int) * NADJ * N_NODES, stream);
    hist_kernel<<<(NADJ * N_EDGES + 255) / 256, 256, 0, stream>>>(adj, counts);
    scan_kernel<<<NADJ, 256, 0, stream>>>(counts, row_start);
    range_scatter_kernel<<<NADJ * NBUCK, 256, 0, stream>>>(adj, row_start, esrc);
    dinv_kernel<<<(NADJ * N_NODES + 255) / 256, 256, 0, stream>>>(row_start, dinv);

    convx_kernel<<<(N_NODES * FDIM / 4 + 255) / 256, 256, 0, stream>>>(x, xb);
    convw_kernel<<<(5 * 65536 + 4 * 48 * 256 + 255) / 256, 256, 0, stream>>>(
        W_convs, W_extra, W_extra2, W_cls, Wt, Wct);

    int agg_grid = (N_NODES + 3) / 4;
    int ga_grid = N_NODES / 16;                 // 3125
    int cls_grid = (N_NODES + 63) / 64;         // 782

    // jump branches: z_i = relu(agg_{i+1}(x) @ W_i + b_i) * mask[i]
    for (int i = 0; i < 3; ++i) {
        int a = i + 1;
        agg_kernel<<<agg_grid, 256, 0, stream>>>(xb, row_start + a * (N_NODES + 1),
                                                 esrc + (size_t)a * N_EDGES,
                                                 dinv + a * N_NODES, gb);
        gemm_act_mfma<<<ga_grid, 256, 0, stream>>>(gb, Wt + (size_t)i * 65536,
                                                   b_convs + i * FDIM,
                                                   nullptr, nullptr, nullptr, nullptr,
                                                   att, i, 0, actb);
        gemm_cls_mfma<<<cls_grid, 256, 0, stream>>>(actb, Wct + (size_t)i * 48 * 256,
                                                    b_cls, logits, i == 0 ? 1 : 0);
    }
    // extra branch (two GCN layers on adj[0])
    agg_kernel<<<agg_grid, 256, 0, stream>>>(xb, row_start, esrc, dinv, gb);
    gemm_act_mfma<<<ga_grid, 256, 0, stream>>>(gb, Wt + (size_t)3 * 65536, b_extra,
                                               bn1_g, bn1_b, bn1_m, bn1_v, att, 3, 1, e1b);
    agg_kernel<<<agg_grid, 256, 0, stream>>>(e1b, row_start, esrc, dinv, gb);
    gemm_act_mfma<<<ga_grid, 256, 0, stream>>>(gb, Wt + (size_t)4 * 65536, b_extra2,
                                               bn2_g, bn2_b, bn2_m, bn2_v, att, 3, 2, actb);
    gemm_cls_mfma<<<cls_grid, 256, 0, stream>>>(actb, Wct + (size_t)3 * 48 * 256,
                                                b_cls, logits, 0);

    lsm_kernel<<<(N_NODES + 3) / 4, 256, 0, stream>>>(logits, out);
}

// Round 5
// 1674.321 us; speedup vs baseline: 1.3014x; 1.2141x over previous
//
#include <hip/hip_runtime.h>
#include <math.h>

#define N_NODES 50000
#define N_EDGES 800000
#define NADJ 4
#define FDIM 256
#define CDIM 40
#define BN_EPS 1e-5f
#define NBUCK 64
#define BUCK_SZ 782   // ceil(50000/64)
#define SC_CHUNKS 8
#define E4_PER_CHUNK (N_EDGES / 4 / SC_CHUNKS)   // 25000

typedef __attribute__((ext_vector_type(8))) short short8;
typedef __attribute__((ext_vector_type(4))) float f32x4;

__device__ __forceinline__ float bf2f(unsigned short u) {
    union { unsigned int i; float f; } c; c.i = ((unsigned int)u) << 16; return c.f;
}
__device__ __forceinline__ unsigned short f2bf(float f) {
    union { float f; unsigned int i; } c; c.f = f;
    unsigned int u = c.i;
    u += 0x7fffu + ((u >> 16) & 1u);
    return (unsigned short)(u >> 16);
}

// ---------------------------------------------------------------- CSR build
__global__ void hist_kernel(const int* __restrict__ adj, int* __restrict__ counts) {
    int idx = blockIdx.x * blockDim.x + threadIdx.x;
    if (idx >= NADJ * N_EDGES) return;
    int a = idx / N_EDGES;
    int e = idx - a * N_EDGES;
    int dst = adj[(size_t)a * 2 * N_EDGES + N_EDGES + e];
    atomicAdd(&counts[a * N_NODES + dst], 1);
}

// writes row_start (inclusive-from-0 CSR offsets) AND cursor (exclusive copy)
__global__ __launch_bounds__(256) void scan_kernel(const int* __restrict__ counts,
                                                   int* __restrict__ row_start,
                                                   int* __restrict__ cursor) {
    int a = blockIdx.x;
    __shared__ int wsum[4];
    __shared__ int carry;
    int lane = threadIdx.x & 63;
    int wid = threadIdx.x >> 6;   // 0..3
    if (threadIdx.x == 0) { carry = 0; row_start[a * (N_NODES + 1)] = 0; }
    __syncthreads();
    for (int base = 0; base < N_NODES; base += 256) {
        int i = base + threadIdx.x;
        int v = (i < N_NODES) ? counts[a * N_NODES + i] : 0;
        int x = v;
        #pragma unroll
        for (int off = 1; off < 64; off <<= 1) {
            int t = __shfl_up(x, off);
            if (lane >= off) x += t;
        }
        if (lane == 63) wsum[wid] = x;
        __syncthreads();
        if (threadIdx.x == 0) {
            int s = 0;
            #pragma unroll
            for (int w = 0; w < 4; ++w) { int t = wsum[w]; wsum[w] = s; s = t + s; }
        }
        __syncthreads();
        int inc = x + wsum[wid] + carry;   // inclusive global prefix
        if (i < N_NODES) {
            row_start[a * (N_NODES + 1) + i + 1] = inc;
            cursor[a * N_NODES + i] = inc - v;   // exclusive
        }
        __syncthreads();
        if (threadIdx.x == 255) carry = inc;
        __syncthreads();
    }
}

// bucketed + chunked scatter: block (a, b, c) scans edge-chunk c of adjacency
// a and scatters edges whose dst lies in bucket b's range via global cursors.
// Write locality comes from the bucket filter; parallelism from the chunks.
__global__ __launch_bounds__(256) void range_scatter_kernel(
        const int* __restrict__ adj, int* __restrict__ cursor,
        unsigned short* __restrict__ esrc) {
    int c = blockIdx.x & (SC_CHUNKS - 1);
    int b = (blockIdx.x >> 3) & (NBUCK - 1);
    int a = blockIdx.x >> 9;
    int lo = b * BUCK_SZ;
    int hi = lo + BUCK_SZ; if (hi > N_NODES) hi = N_NODES;
    const int* dsts = adj + (size_t)a * 2 * N_EDGES + N_EDGES;
    const int* srcs = adj + (size_t)a * 2 * N_EDGES;
    unsigned short* eout = esrc + (size_t)a * N_EDGES;
    int* cur = cursor + a * N_NODES;
    int e4lo = c * E4_PER_CHUNK;
    int e4hi = e4lo + E4_PER_CHUNK;
    for (int e4 = e4lo + threadIdx.x; e4 < e4hi; e4 += 256) {
        int4 d = reinterpret_cast<const int4*>(dsts)[e4];
        int e = e4 * 4;
        if (d.x >= lo && d.x < hi) { int p = atomicAdd(&cur[d.x], 1); eout[p] = (unsigned short)srcs[e + 0]; }
        if (d.y >= lo && d.y < hi) { int p = atomicAdd(&cur[d.y], 1); eout[p] = (unsigned short)srcs[e + 1]; }
        if (d.z >= lo && d.z < hi) { int p = atomicAdd(&cur[d.z], 1); eout[p] = (unsigned short)srcs[e + 2]; }
        if (d.w >= lo && d.w < hi) { int p = atomicAdd(&cur[d.w], 1); eout[p] = (unsigned short)srcs[e + 3]; }
    }
}

__global__ void dinv_kernel(const int* __restrict__ row_start, float* __restrict__ dinv) {
    int idx = blockIdx.x * blockDim.x + threadIdx.x;
    if (idx >= NADJ * N_NODES) return;
    int a = idx / N_NODES;
    int n = idx - a * N_NODES;
    int d = row_start[a * (N_NODES + 1) + n + 1] - row_start[a * (N_NODES + 1) + n] + 1;
    dinv[idx] = rsqrtf((float)d);
}

// ------------------------------------------------------------- conversions
// x [N,256] fp32 -> xb bf16
__global__ void convx_kernel(const float* __restrict__ x, unsigned short* __restrict__ xb) {
    int i = blockIdx.x * blockDim.x + threadIdx.x;   // one float4 per thread
    if (i >= N_NODES * FDIM / 4) return;
    float4 v = *reinterpret_cast<const float4*>(&x[(size_t)i * 4]);
    ushort4 o;
    o.x = f2bf(v.x); o.y = f2bf(v.y); o.z = f2bf(v.z); o.w = f2bf(v.w);
    *reinterpret_cast<ushort4*>(&xb[(size_t)i * 4]) = o;
}

// weights -> transposed bf16.  Wt[5][256][256]: Wt[w][n][k] = Wsrc[w][k][n]
// Wct[4][48][256]: Wct[b][c][k] = c<40 ? W_cls[(b*256+k)*40+c] : 0
__global__ void convw_kernel(const float* __restrict__ W_convs, const float* __restrict__ W_extra,
                             const float* __restrict__ W_extra2, const float* __restrict__ W_cls,
                             unsigned short* __restrict__ Wt, unsigned short* __restrict__ Wct) {
    int idx = blockIdx.x * blockDim.x + threadIdx.x;
    const int NSQ = 5 * 65536;
    if (idx < NSQ) {
        int w = idx >> 16;
        int rem = idx & 65535;
        int n = rem >> 8;
        int k = rem & 255;
        const float* src = (w < 3) ? (W_convs + (size_t)w * 65536)
                                   : ((w == 3) ? W_extra : W_extra2);
        Wt[idx] = f2bf(src[(size_t)k * 256 + n]);
    } else if (idx < NSQ + 4 * 48 * 256) {
        int rem = idx - NSQ;
        int b = rem / (48 * 256);
        int r2 = rem - b * (48 * 256);
        int c = r2 >> 8;
        int k = r2 & 255;
        float v = (c < CDIM) ? W_cls[((size_t)b * 256 + k) * CDIM + c] : 0.0f;
        Wct[rem] = f2bf(v);
    }
}

// ------------------------------------------------------------- aggregation
// one wave per node; lane handles 4 features (8B ushort4 loads)
// g[n] = sum_{e: dst=n} dinv[src]*dinv[n]*xin[src] + dinv[n]^2 * xin[n]
__global__ __launch_bounds__(256) void agg_kernel(
        const unsigned short* __restrict__ xb, const int* __restrict__ row_start,
        const unsigned short* __restrict__ esrc, const float* __restrict__ dinv,
        unsigned short* __restrict__ gout) {
    int lane = threadIdx.x & 63;
    int n = blockIdx.x * 4 + (threadIdx.x >> 6);
    if (n >= N_NODES) return;
    int beg = row_start[n];
    int end = row_start[n + 1];
    float dn = dinv[n];
    size_t fo = (size_t)lane * 4;
    ushort4 sv = *reinterpret_cast<const ushort4*>(&xb[(size_t)n * FDIM + fo]);
    float ws = dn * dn;
    float a0 = ws * bf2f(sv.x), a1 = ws * bf2f(sv.y), a2 = ws * bf2f(sv.z), a3 = ws * bf2f(sv.w);
    for (int p = beg; p < end; ++p) {
        int s = (int)esrc[p];
        float w = dn * dinv[s];
        ushort4 v = *reinterpret_cast<const ushort4*>(&xb[(size_t)s * FDIM + fo]);
        a0 += w * bf2f(v.x); a1 += w * bf2f(v.y); a2 += w * bf2f(v.z); a3 += w * bf2f(v.w);
    }
    ushort4 o;
    o.x = f2bf(a0); o.y = f2bf(a1); o.z = f2bf(a2); o.w = f2bf(a3);
    *reinterpret_cast<ushort4*>(&gout[(size_t)n * FDIM + fo]) = o;
}

// ------------------------------------------------ branch GEMM via MFMA bf16
// out = epilogue(A[N,256] @ W[256,256] + bias), A bf16, Wt = W^T bf16 [n][k]
// block: 256 thr = 4 waves; wave w -> cols [w*64, w*64+64); block -> 16 rows
// mode 0: relu(y+b)*mask[branch]; 1: relu(bn1(y+b)); 2: relu(bn2(y+b))*mask[3]
__global__ __launch_bounds__(256) void gemm_act_mfma(
        const unsigned short* __restrict__ A, const unsigned short* __restrict__ Wt,
        const float* __restrict__ bias,
        const float* __restrict__ gamma, const float* __restrict__ beta,
        const float* __restrict__ mean, const float* __restrict__ var,
        const float* __restrict__ att, int branch, int mode,
        unsigned short* __restrict__ outb) {
    int lane = threadIdx.x & 63;
    int wv = threadIdx.x >> 6;
    int row0 = blockIdx.x * 16;          // 3125 blocks * 16 = 50000 exactly
    int n0 = wv * 64;
    int r = lane & 15;
    int g = lane >> 4;
    f32x4 acc[4] = {{0.f,0.f,0.f,0.f},{0.f,0.f,0.f,0.f},{0.f,0.f,0.f,0.f},{0.f,0.f,0.f,0.f}};
    const unsigned short* arow = A + (size_t)(row0 + r) * 256 + g * 8;
    #pragma unroll
    for (int t = 0; t < 8; ++t) {
        short8 a = *reinterpret_cast<const short8*>(arow + t * 32);
        #pragma unroll
        for (int f = 0; f < 4; ++f) {
            short8 b = *reinterpret_cast<const short8*>(
                Wt + (size_t)(n0 + f * 16 + r) * 256 + t * 32 + g * 8);
            acc[f] = __builtin_amdgcn_mfma_f32_16x16x32_bf16(a, b, acc[f], 0, 0, 0);
        }
    }
    float m4 = 1.0f;
    if (mode == 0 || mode == 2) {
        float c0 = att[0], c1 = att[1], c2 = att[2], c3 = att[3];
        float mx = fmaxf(fmaxf(c0, c1), fmaxf(c2, c3));
        float e0 = expf(c0 - mx), e1 = expf(c1 - mx), e2 = expf(c2 - mx), e3 = expf(c3 - mx);
        float s = e0 + e1 + e2 + e3;
        float sel = (branch == 0) ? e0 : (branch == 1) ? e1 : (branch == 2) ? e2 : e3;
        m4 = sel / s;
    }
    #pragma unroll
    for (int f = 0; f < 4; ++f) {
        int col = n0 + f * 16 + r;
        float bi = bias[col];
        float mu = 0.f, rs = 1.f, ga = 1.f, be = 0.f;
        if (mode >= 1) {
            mu = mean[col]; rs = rsqrtf(var[col] + BN_EPS); ga = gamma[col]; be = beta[col];
        }
        #pragma unroll
        for (int j = 0; j < 4; ++j) {
            int row = row0 + g * 4 + j;
            float y = acc[f][j] + bi;
            if (mode >= 1) y = (y - mu) * rs * ga + be;
            y = fmaxf(y, 0.0f) * m4;
            outb[(size_t)row * 256 + col] = f2bf(y);
        }
    }
}

// -------------------------------------- classifier partial GEMM into logits
// logits[N,40] (+)= A[N,256] @ Wc[256,40]; Wct [48][256] bf16 (cols 40..47 zero)
// block: 4 waves, wave w -> rows [blk*64 + w*16, +16), cols 0..47
__global__ __launch_bounds__(256) void gemm_cls_mfma(
        const unsigned short* __restrict__ A, const unsigned short* __restrict__ Wct,
        const float* __restrict__ bcls, float* __restrict__ logits, int first) {
    int lane = threadIdx.x & 63;
    int wv = threadIdx.x >> 6;
    int row0 = blockIdx.x * 64 + wv * 16;
    int r = lane & 15;
    int g = lane >> 4;
    f32x4 acc[3] = {{0.f,0.f,0.f,0.f},{0.f,0.f,0.f,0.f},{0.f,0.f,0.f,0.f}};
    int ar = row0 + r; if (ar > N_NODES - 1) ar = N_NODES - 1;
    const unsigned short* arow = A + (size_t)ar * 256 + g * 8;
    #pragma unroll
    for (int t = 0; t < 8; ++t) {
        short8 a = *reinterpret_cast<const short8*>(arow + t * 32);
        #pragma unroll
        for (int f = 0; f < 3; ++f) {
            short8 b = *reinterpret_cast<const short8*>(
                Wct + (size_t)(f * 16 + r) * 256 + t * 32 + g * 8);
            acc[f] = __builtin_amdgcn_mfma_f32_16x16x32_bf16(a, b, acc[f], 0, 0, 0);
        }
    }
    #pragma unroll
    for (int f = 0; f < 3; ++f) {
        int col = f * 16 + r;
        if (col >= CDIM) continue;
        float bi = bcls[col];
        #pragma unroll
        for (int j = 0; j < 4; ++j) {
            int row = row0 + g * 4 + j;
            if (row >= N_NODES) continue;
            float v = acc[f][j];
            if (first) logits[(size_t)row * CDIM + col] = v + bi;
            else       logits[(size_t)row * CDIM + col] += v;
        }
    }
}

// ----------------------------------------------------------- log_softmax
__global__ void lsm_kernel(const float* __restrict__ logits, float* __restrict__ out) {
    int n = blockIdx.x * 4 + (threadIdx.x >> 6);
    int lane = threadIdx.x & 63;
    if (blockIdx.x == 0 && threadIdx.x == 0)
        out[(size_t)N_NODES * CDIM] = 0.0f;   // trailing scalar output
    if (n >= N_NODES) return;
    float v = (lane < CDIM) ? logits[(size_t)n * CDIM + lane] : -INFINITY;
    float m = v;
    #pragma unroll
    for (int off = 32; off >= 1; off >>= 1) m = fmaxf(m, __shfl_xor(m, off));
    float ex = (lane < CDIM) ? expf(v - m) : 0.0f;
    float s = ex;
    #pragma unroll
    for (int off = 32; off >= 1; off >>= 1) s += __shfl_xor(s, off);
    float ls = logf(s) + m;
    if (lane < CDIM) out[(size_t)n * CDIM + lane] = v - ls;
}

// ------------------------------------------------------------------ launch
extern "C" void kernel_launch(void* const* d_in, const int* in_sizes, int n_in,
                              void* d_out, int out_size, void* d_ws, size_t ws_size,
                              hipStream_t stream) {
    const float* x        = (const float*)d_in[0];
    const int*   adj      = (const int*)d_in[1];
    const float* W_convs  = (const float*)d_in[2];
    const float* b_convs  = (const float*)d_in[3];
    const float* W_extra  = (const float*)d_in[4];
    const float* b_extra  = (const float*)d_in[5];
    const float* bn1_g    = (const float*)d_in[6];
    const float* bn1_b    = (const float*)d_in[7];
    const float* bn1_m    = (const float*)d_in[8];
    const float* bn1_v    = (const float*)d_in[9];
    const float* W_extra2 = (const float*)d_in[10];
    const float* b_extra2 = (const float*)d_in[11];
    const float* bn2_g    = (const float*)d_in[12];
    const float* bn2_b    = (const float*)d_in[13];
    const float* bn2_m    = (const float*)d_in[14];
    const float* bn2_v    = (const float*)d_in[15];
    const float* att      = (const float*)d_in[16];
    const float* W_cls    = (const float*)d_in[17];
    const float* b_cls    = (const float*)d_in[18];
    float* out = (float*)d_out;

    char* base = (char*)d_ws;
    size_t off = 0;
    auto carve = [&](size_t bytes) -> char* {
        char* p = base + off;
        off = (off + bytes + 255) & ~(size_t)255;
        return p;
    };
    int*   row_start = (int*)carve(sizeof(int) * NADJ * (N_NODES + 1));
    int*   counts    = (int*)carve(sizeof(int) * NADJ * N_NODES);
    int*   cursor    = (int*)carve(sizeof(int) * NADJ * N_NODES);
    unsigned short* esrc = (unsigned short*)carve(sizeof(short) * (size_t)NADJ * N_EDGES);
    float* dinv      = (float*)carve(sizeof(float) * NADJ * N_NODES);
    unsigned short* xb   = (unsigned short*)carve(sizeof(short) * (size_t)N_NODES * FDIM);
    unsigned short* gb   = (unsigned short*)carve(sizeof(short) * (size_t)N_NODES * FDIM);
    unsigned short* actb = (unsigned short*)carve(sizeof(short) * (size_t)N_NODES * FDIM);
    unsigned short* e1b  = (unsigned short*)carve(sizeof(short) * (size_t)N_NODES * FDIM);
    unsigned short* Wt   = (unsigned short*)carve(sizeof(short) * 5 * 65536);
    unsigned short* Wct  = (unsigned short*)carve(sizeof(short) * 4 * 48 * 256);
    float* logits    = (float*)carve(sizeof(float) * (size_t)N_NODES * CDIM);

    hipMemsetAsync(counts, 0, sizeof(int) * NADJ * N_NODES, stream);
    hist_kernel<<<(NADJ * N_EDGES + 255) / 256, 256, 0, stream>>>(adj, counts);
    scan_kernel<<<NADJ, 256, 0, stream>>>(counts, row_start, cursor);
    range_scatter_kernel<<<NADJ * NBUCK * SC_CHUNKS, 256, 0, stream>>>(adj, cursor, esrc);
    dinv_kernel<<<(NADJ * N_NODES + 255) / 256, 256, 0, stream>>>(row_start, dinv);

    convx_kernel<<<(N_NODES * FDIM / 4 + 255) / 256, 256, 0, stream>>>(x, xb);
    convw_kernel<<<(5 * 65536 + 4 * 48 * 256 + 255) / 256, 256, 0, stream>>>(
        W_convs, W_extra, W_extra2, W_cls, Wt, Wct);

    int agg_grid = (N_NODES + 3) / 4;
    int ga_grid = N_NODES / 16;                 // 3125
    int cls_grid = (N_NODES + 63) / 64;         // 782

    // jump branches: z_i = relu(agg_{i+1}(x) @ W_i + b_i) * mask[i]
    for (int i = 0; i < 3; ++i) {
        int a = i + 1;
        agg_kernel<<<agg_grid, 256, 0, stream>>>(xb, row_start + a * (N_NODES + 1),
                                                 esrc + (size_t)a * N_EDGES,
                                                 dinv + a * N_NODES, gb);
        gemm_act_mfma<<<ga_grid, 256, 0, stream>>>(gb, Wt + (size_t)i * 65536,
                                                   b_convs + i * FDIM,
                                                   nullptr, nullptr, nullptr, nullptr,
                                                   att, i, 0, actb);
        gemm_cls_mfma<<<cls_grid, 256, 0, stream>>>(actb, Wct + (size_t)i * 48 * 256,
                                                    b_cls, logits, i == 0 ? 1 : 0);
    }
    // extra branch (two GCN layers on adj[0])
    agg_kernel<<<agg_grid, 256, 0, stream>>>(xb, row_start, esrc, dinv, gb);
    gemm_act_mfma<<<ga_grid, 256, 0, stream>>>(gb, Wt + (size_t)3 * 65536, b_extra,
                                               bn1_g, bn1_b, bn1_m, bn1_v, att, 3, 1, e1b);
    agg_kernel<<<agg_grid, 256, 0, stream>>>(e1b, row_start, esrc, dinv, gb);
    gemm_act_mfma<<<ga_grid, 256, 0, stream>>>(gb, Wt + (size_t)4 * 65536, b_extra2,
                                               bn2_g, bn2_b, bn2_m, bn2_v, att, 3, 2, actb);
    gemm_cls_mfma<<<cls_grid, 256, 0, stream>>>(actb, Wct + (size_t)3 * 48 * 256,
                                                b_cls, logits, 0);

    lsm_kernel<<<(N_NODES + 3) / 4, 256, 0, stream>>>(logits, out);
}

// Round 7
// 1379.466 us; speedup vs baseline: 1.5796x; 1.2137x over previous
//
#include <hip/hip_runtime.h>
#include <math.h>

#define N_NODES 50000
#define N_EDGES 800000
#define NADJ 4
#define FDIM 256
#define CDIM 40
#define BN_EPS 1e-5f
#define NBUCK 64
#define BUCK_SZ 782            // ceil(50000/64); 64*782 = 50048
#define NCHUNK 64
#define EPC (N_EDGES / NCHUNK) // 12500 edges per chunk

typedef __attribute__((ext_vector_type(8))) short short8;
typedef __attribute__((ext_vector_type(4))) float f32x4;

__device__ __forceinline__ float bf2f(unsigned short u) {
    union { unsigned int i; float f; } c; c.i = ((unsigned int)u) << 16; return c.f;
}
__device__ __forceinline__ unsigned short f2bf(float f) {
    union { float f; unsigned int i; } c; c.f = f;
    unsigned int u = c.i;
    u += 0x7fffu + ((u >> 16) & 1u);
    return (unsigned short)(u >> 16);
}

// ================================================================ CSR build
// Stage 1: per-chunk bucket histogram (LDS only, no global atomics)
__global__ __launch_bounds__(256) void bucket_hist_kernel(const int* __restrict__ adj,
                                                          int* __restrict__ bh) {
    __shared__ int cnt[NBUCK];
    int a = blockIdx.x >> 6;
    int c = blockIdx.x & (NCHUNK - 1);
    if (threadIdx.x < NBUCK) cnt[threadIdx.x] = 0;
    __syncthreads();
    const int* dsts = adj + (size_t)a * 2 * N_EDGES + N_EDGES + c * EPC;
    for (int e = threadIdx.x; e < EPC; e += 256)
        atomicAdd(&cnt[dsts[e] / BUCK_SZ], 1);
    __syncthreads();
    if (threadIdx.x < NBUCK)
        bh[(a * NBUCK + threadIdx.x) * NCHUNK + c] = cnt[threadIdx.x];
}

// Stage 2: exclusive scan of 4096 (b-major, c-minor) counts per adjacency
__global__ __launch_bounds__(256) void bucket_scan_kernel(const int* __restrict__ bh,
                                                          int* __restrict__ boff) {
    int a = blockIdx.x;
    __shared__ int wsum[4];
    __shared__ int carry;
    int lane = threadIdx.x & 63;
    int wid = threadIdx.x >> 6;
    if (threadIdx.x == 0) carry = 0;
    __syncthreads();
    for (int base = 0; base < NBUCK * NCHUNK; base += 256) {
        int j = base + threadIdx.x;
        int v = bh[a * NBUCK * NCHUNK + j];
        int x = v;
        #pragma unroll
        for (int off = 1; off < 64; off <<= 1) {
            int t = __shfl_up(x, off);
            if (lane >= off) x += t;
        }
        if (lane == 63) wsum[wid] = x;
        __syncthreads();
        if (threadIdx.x == 0) {
            int s = 0;
            #pragma unroll
            for (int w = 0; w < 4; ++w) { int t = wsum[w]; wsum[w] = s; s = t + s; }
        }
        __syncthreads();
        int inc = x + wsum[wid] + carry;
        boff[a * NBUCK * NCHUNK + j] = inc - v;   // exclusive
        __syncthreads();
        if (threadIdx.x == 255) carry = inc;
        __syncthreads();
    }
}

// Stage 3: scatter edges into bucket-grouped buffer (packed (dst<<16)|src).
// Block (a,c) writes each bucket's edges into its private contiguous subrange.
__global__ __launch_bounds__(256) void bucket_scatter_kernel(
        const int* __restrict__ adj, const int* __restrict__ boff,
        unsigned int* __restrict__ gbuf) {
    __shared__ int base[NBUCK];
    __shared__ int cnt[NBUCK];
    int a = blockIdx.x >> 6;
    int c = blockIdx.x & (NCHUNK - 1);
    if (threadIdx.x < NBUCK)
        base[threadIdx.x] = boff[(a * NBUCK + threadIdx.x) * NCHUNK + c];
    const int* dsts = adj + (size_t)a * 2 * N_EDGES + N_EDGES + c * EPC;
    const int* srcs = adj + (size_t)a * 2 * N_EDGES + c * EPC;
    unsigned int* gout = gbuf + (size_t)a * N_EDGES;
    for (int t0 = 0; t0 < EPC; t0 += 256) {
        if (threadIdx.x < NBUCK) cnt[threadIdx.x] = 0;
        __syncthreads();
        int e = t0 + threadIdx.x;
        int b = -1, r = 0; unsigned int pk = 0;
        if (e < EPC) {
            int d = dsts[e];
            int s = srcs[e];
            b = d / BUCK_SZ;
            pk = ((unsigned int)d << 16) | (unsigned int)s;
            r = atomicAdd(&cnt[b], 1);
        }
        __syncthreads();
        if (b >= 0) gout[base[b] + r] = pk;
        __syncthreads();
        if (threadIdx.x < NBUCK) base[threadIdx.x] += cnt[threadIdx.x];
        __syncthreads();
    }
}

// Stage 4: per-dst counts from bucketed edges (LDS counters, coalesced write)
__global__ __launch_bounds__(256) void count_kernel(const unsigned int* __restrict__ gbuf,
                                                    const int* __restrict__ boff,
                                                    int* __restrict__ counts) {
    __shared__ int cnt[BUCK_SZ];
    int a = blockIdx.x >> 6;
    int b = blockIdx.x & (NBUCK - 1);
    int lo = b * BUCK_SZ;
    int hi = lo + BUCK_SZ; if (hi > N_NODES) hi = N_NODES;
    int nloc = hi - lo;
    for (int i = threadIdx.x; i < BUCK_SZ; i += 256) cnt[i] = 0;
    __syncthreads();
    int bs = boff[(a * NBUCK + b) * NCHUNK];
    int be = (b == NBUCK - 1) ? N_EDGES : boff[(a * NBUCK + b + 1) * NCHUNK];
    const unsigned int* g = gbuf + (size_t)a * N_EDGES;
    for (int p = bs + threadIdx.x; p < be; p += 256)
        atomicAdd(&cnt[(g[p] >> 16) - lo], 1);
    __syncthreads();
    for (int i = threadIdx.x; i < nloc; i += 256)
        counts[a * N_NODES + lo + i] = cnt[i];
}

// Stage 5: CSR row offsets
__global__ __launch_bounds__(256) void scan_kernel(const int* __restrict__ counts,
                                                   int* __restrict__ row_start) {
    int a = blockIdx.x;
    __shared__ int wsum[4];
    __shared__ int carry;
    int lane = threadIdx.x & 63;
    int wid = threadIdx.x >> 6;
    if (threadIdx.x == 0) { carry = 0; row_start[a * (N_NODES + 1)] = 0; }
    __syncthreads();
    for (int base = 0; base < N_NODES; base += 256) {
        int i = base + threadIdx.x;
        int v = (i < N_NODES) ? counts[a * N_NODES + i] : 0;
        int x = v;
        #pragma unroll
        for (int off = 1; off < 64; off <<= 1) {
            int t = __shfl_up(x, off);
            if (lane >= off) x += t;
        }
        if (lane == 63) wsum[wid] = x;
        __syncthreads();
        if (threadIdx.x == 0) {
            int s = 0;
            #pragma unroll
            for (int w = 0; w < 4; ++w) { int t = wsum[w]; wsum[w] = s; s = t + s; }
        }
        __syncthreads();
        int inc = x + wsum[wid] + carry;
        if (i < N_NODES) row_start[a * (N_NODES + 1) + i + 1] = inc;
        __syncthreads();
        if (threadIdx.x == 255) carry = inc;
        __syncthreads();
    }
}

// Stage 6: final CSR scatter — block (a,b) owns its 25KB esrc region
__global__ __launch_bounds__(256) void scatter2_kernel(const unsigned int* __restrict__ gbuf,
                                                       const int* __restrict__ boff,
                                                       const int* __restrict__ row_start,
                                                       unsigned short* __restrict__ esrc) {
    __shared__ int cur[BUCK_SZ];
    int a = blockIdx.x >> 6;
    int b = blockIdx.x & (NBUCK - 1);
    int lo = b * BUCK_SZ;
    int hi = lo + BUCK_SZ; if (hi > N_NODES) hi = N_NODES;
    int nloc = hi - lo;
    for (int i = threadIdx.x; i < nloc; i += 256)
        cur[i] = row_start[a * (N_NODES + 1) + lo + i];
    __syncthreads();
    int bs = boff[(a * NBUCK + b) * NCHUNK];
    int be = (b == NBUCK - 1) ? N_EDGES : boff[(a * NBUCK + b + 1) * NCHUNK];
    const unsigned int* g = gbuf + (size_t)a * N_EDGES;
    unsigned short* eout = esrc + (size_t)a * N_EDGES;
    for (int p = bs + threadIdx.x; p < be; p += 256) {
        unsigned int pk = g[p];
        int pos = atomicAdd(&cur[(pk >> 16) - lo], 1);
        eout[pos] = (unsigned short)(pk & 0xffffu);
    }
}

__global__ void dinv_kernel(const int* __restrict__ row_start, float* __restrict__ dinv) {
    int idx = blockIdx.x * blockDim.x + threadIdx.x;
    if (idx >= NADJ * N_NODES) return;
    int a = idx / N_NODES;
    int n = idx - a * N_NODES;
    int d = row_start[a * (N_NODES + 1) + n + 1] - row_start[a * (N_NODES + 1) + n] + 1;
    dinv[idx] = rsqrtf((float)d);
}

// ------------------------------------------------------------- conversions
__global__ void convx_kernel(const float* __restrict__ x, unsigned short* __restrict__ xb) {
    int i = blockIdx.x * blockDim.x + threadIdx.x;
    if (i >= N_NODES * FDIM / 4) return;
    float4 v = *reinterpret_cast<const float4*>(&x[(size_t)i * 4]);
    ushort4 o;
    o.x = f2bf(v.x); o.y = f2bf(v.y); o.z = f2bf(v.z); o.w = f2bf(v.w);
    *reinterpret_cast<ushort4*>(&xb[(size_t)i * 4]) = o;
}

// weights -> transposed bf16.  Wt[5][256][256]: Wt[w][n][k] = Wsrc[w][k][n]
// Wct[4][48][256]: Wct[b][c][k] = c<40 ? W_cls[(b*256+k)*40+c] : 0
__global__ void convw_kernel(const float* __restrict__ W_convs, const float* __restrict__ W_extra,
                             const float* __restrict__ W_extra2, const float* __restrict__ W_cls,
                             unsigned short* __restrict__ Wt, unsigned short* __restrict__ Wct) {
    int idx = blockIdx.x * blockDim.x + threadIdx.x;
    const int NSQ = 5 * 65536;
    if (idx < NSQ) {
        int w = idx >> 16;
        int rem = idx & 65535;
        int n = rem >> 8;
        int k = rem & 255;
        const float* src = (w < 3) ? (W_convs + (size_t)w * 65536)
                                   : ((w == 3) ? W_extra : W_extra2);
        Wt[idx] = f2bf(src[(size_t)k * 256 + n]);
    } else if (idx < NSQ + 4 * 48 * 256) {
        int rem = idx - NSQ;
        int b = rem / (48 * 256);
        int r2 = rem - b * (48 * 256);
        int c = r2 >> 8;
        int k = r2 & 255;
        float v = (c < CDIM) ? W_cls[((size_t)b * 256 + k) * CDIM + c] : 0.0f;
        Wct[rem] = f2bf(v);
    }
}

// ------------------------------------------------------------- aggregation
// one wave per node; lane handles 4 features (8B ushort4 loads)
__global__ __launch_bounds__(256) void agg_kernel(
        const unsigned short* __restrict__ xb, const int* __restrict__ row_start,
        const unsigned short* __restrict__ esrc, const float* __restrict__ dinv,
        unsigned short* __restrict__ gout) {
    int lane = threadIdx.x & 63;
    int n = blockIdx.x * 4 + (threadIdx.x >> 6);
    if (n >= N_NODES) return;
    int beg = row_start[n];
    int end = row_start[n + 1];
    float dn = dinv[n];
    size_t fo = (size_t)lane * 4;
    ushort4 sv = *reinterpret_cast<const ushort4*>(&xb[(size_t)n * FDIM + fo]);
    float ws = dn * dn;
    float a0 = ws * bf2f(sv.x), a1 = ws * bf2f(sv.y), a2 = ws * bf2f(sv.z), a3 = ws * bf2f(sv.w);
    for (int p = beg; p < end; ++p) {
        int s = (int)esrc[p];
        float w = dn * dinv[s];
        ushort4 v = *reinterpret_cast<const ushort4*>(&xb[(size_t)s * FDIM + fo]);
        a0 += w * bf2f(v.x); a1 += w * bf2f(v.y); a2 += w * bf2f(v.z); a3 += w * bf2f(v.w);
    }
    ushort4 o;
    o.x = f2bf(a0); o.y = f2bf(a1); o.z = f2bf(a2); o.w = f2bf(a3);
    *reinterpret_cast<ushort4*>(&gout[(size_t)n * FDIM + fo]) = o;
}

// ------------------------------------------------ branch GEMM via MFMA bf16
__global__ __launch_bounds__(256) void gemm_act_mfma(
        const unsigned short* __restrict__ A, const unsigned short* __restrict__ Wt,
        const float* __restrict__ bias,
        const float* __restrict__ gamma, const float* __restrict__ beta,
        const float* __restrict__ mean, const float* __restrict__ var,
        const float* __restrict__ att, int branch, int mode,
        unsigned short* __restrict__ outb) {
    int lane = threadIdx.x & 63;
    int wv = threadIdx.x >> 6;
    int row0 = blockIdx.x * 16;          // 3125 blocks * 16 = 50000 exactly
    int n0 = wv * 64;
    int r = lane & 15;
    int g = lane >> 4;
    f32x4 acc[4] = {{0.f,0.f,0.f,0.f},{0.f,0.f,0.f,0.f},{0.f,0.f,0.f,0.f},{0.f,0.f,0.f,0.f}};
    const unsigned short* arow = A + (size_t)(row0 + r) * 256 + g * 8;
    #pragma unroll
    for (int t = 0; t < 8; ++t) {
        short8 a = *reinterpret_cast<const short8*>(arow + t * 32);
        #pragma unroll
        for (int f = 0; f < 4; ++f) {
            short8 b = *reinterpret_cast<const short8*>(
                Wt + (size_t)(n0 + f * 16 + r) * 256 + t * 32 + g * 8);
            acc[f] = __builtin_amdgcn_mfma_f32_16x16x32_bf16(a, b, acc[f], 0, 0, 0);
        }
    }
    float m4 = 1.0f;
    if (mode == 0 || mode == 2) {
        float c0 = att[0], c1 = att[1], c2 = att[2], c3 = att[3];
        float mx = fmaxf(fmaxf(c0, c1), fmaxf(c2, c3));
        float e0 = expf(c0 - mx), e1 = expf(c1 - mx), e2 = expf(c2 - mx), e3 = expf(c3 - mx);
        float s = e0 + e1 + e2 + e3;
        float sel = (branch == 0) ? e0 : (branch == 1) ? e1 : (branch == 2) ? e2 : e3;
        m4 = sel / s;
    }
    #pragma unroll
    for (int f = 0; f < 4; ++f) {
        int col = n0 + f * 16 + r;
        float bi = bias[col];
        float mu = 0.f, rs = 1.f, ga = 1.f, be = 0.f;
        if (mode >= 1) {
            mu = mean[col]; rs = rsqrtf(var[col] + BN_EPS); ga = gamma[col]; be = beta[col];
        }
        #pragma unroll
        for (int j = 0; j < 4; ++j) {
            int row = row0 + g * 4 + j;
            float y = acc[f][j] + bi;
            if (mode >= 1) y = (y - mu) * rs * ga + be;
            y = fmaxf(y, 0.0f) * m4;
            outb[(size_t)row * 256 + col] = f2bf(y);
        }
    }
}

// -------------------------------------- classifier partial GEMM into logits
__global__ __launch_bounds__(256) void gemm_cls_mfma(
        const unsigned short* __restrict__ A, const unsigned short* __restrict__ Wct,
        const float* __restrict__ bcls, float* __restrict__ logits, int first) {
    int lane = threadIdx.x & 63;
    int wv = threadIdx.x >> 6;
    int row0 = blockIdx.x * 64 + wv * 16;
    int r = lane & 15;
    int g = lane >> 4;
    f32x4 acc[3] = {{0.f,0.f,0.f,0.f},{0.f,0.f,0.f,0.f},{0.f,0.f,0.f,0.f}};
    int ar = row0 + r; if (ar > N_NODES - 1) ar = N_NODES - 1;
    const unsigned short* arow = A + (size_t)ar * 256 + g * 8;
    #pragma unroll
    for (int t = 0; t < 8; ++t) {
        short8 a = *reinterpret_cast<const short8*>(arow + t * 32);
        #pragma unroll
        for (int f = 0; f < 3; ++f) {
            short8 b = *reinterpret_cast<const short8*>(
                Wct + (size_t)(f * 16 + r) * 256 + t * 32 + g * 8);
            acc[f] = __builtin_amdgcn_mfma_f32_16x16x32_bf16(a, b, acc[f], 0, 0, 0);
        }
    }
    #pragma unroll
    for (int f = 0; f < 3; ++f) {
        int col = f * 16 + r;
        if (col >= CDIM) continue;
        float bi = bcls[col];
        #pragma unroll
        for (int j = 0; j < 4; ++j) {
            int row = row0 + g * 4 + j;
            if (row >= N_NODES) continue;
            float v = acc[f][j];
            if (first) logits[(size_t)row * CDIM + col] = v + bi;
            else       logits[(size_t)row * CDIM + col] += v;
        }
    }
}

// ----------------------------------------------------------- log_softmax
__global__ void lsm_kernel(const float* __restrict__ logits, float* __restrict__ out) {
    int n = blockIdx.x * 4 + (threadIdx.x >> 6);
    int lane = threadIdx.x & 63;
    if (blockIdx.x == 0 && threadIdx.x == 0)
        out[(size_t)N_NODES * CDIM] = 0.0f;   // trailing scalar output
    if (n >= N_NODES) return;
    float v = (lane < CDIM) ? logits[(size_t)n * CDIM + lane] : -INFINITY;
    float m = v;
    #pragma unroll
    for (int off = 32; off >= 1; off >>= 1) m = fmaxf(m, __shfl_xor(m, off));
    float ex = (lane < CDIM) ? expf(v - m) : 0.0f;
    float s = ex;
    #pragma unroll
    for (int off = 32; off >= 1; off >>= 1) s += __shfl_xor(s, off);
    float ls = logf(s) + m;
    if (lane < CDIM) out[(size_t)n * CDIM + lane] = v - ls;
}

// ------------------------------------------------------------------ launch
extern "C" void kernel_launch(void* const* d_in, const int* in_sizes, int n_in,
                              void* d_out, int out_size, void* d_ws, size_t ws_size,
                              hipStream_t stream) {
    const float* x        = (const float*)d_in[0];
    const int*   adj      = (const int*)d_in[1];
    const float* W_convs  = (const float*)d_in[2];
    const float* b_convs  = (const float*)d_in[3];
    const float* W_extra  = (const float*)d_in[4];
    const float* b_extra  = (const float*)d_in[5];
    const float* bn1_g    = (const float*)d_in[6];
    const float* bn1_b    = (const float*)d_in[7];
    const float* bn1_m    = (const float*)d_in[8];
    const float* bn1_v    = (const float*)d_in[9];
    const float* W_extra2 = (const float*)d_in[10];
    const float* b_extra2 = (const float*)d_in[11];
    const float* bn2_g    = (const float*)d_in[12];
    const float* bn2_b    = (const float*)d_in[13];
    const float* bn2_m    = (const float*)d_in[14];
    const float* bn2_v    = (const float*)d_in[15];
    const float* att      = (const float*)d_in[16];
    const float* W_cls    = (const float*)d_in[17];
    const float* b_cls    = (const float*)d_in[18];
    float* out = (float*)d_out;

    char* base = (char*)d_ws;
    size_t off = 0;
    auto carve = [&](size_t bytes) -> char* {
        char* p = base + off;
        off = (off + bytes + 255) & ~(size_t)255;
        return p;
    };
    int*   row_start = (int*)carve(sizeof(int) * NADJ * (N_NODES + 1));
    int*   counts    = (int*)carve(sizeof(int) * NADJ * N_NODES);
    int*   bh        = (int*)carve(sizeof(int) * NADJ * NBUCK * NCHUNK);
    int*   boff      = (int*)carve(sizeof(int) * NADJ * NBUCK * NCHUNK);
    unsigned int* gbuf = (unsigned int*)carve(sizeof(int) * (size_t)NADJ * N_EDGES);
    unsigned short* esrc = (unsigned short*)carve(sizeof(short) * (size_t)NADJ * N_EDGES);
    float* dinv      = (float*)carve(sizeof(float) * NADJ * N_NODES);
    unsigned short* xb   = (unsigned short*)carve(sizeof(short) * (size_t)N_NODES * FDIM);
    unsigned short* gb   = (unsigned short*)carve(sizeof(short) * (size_t)N_NODES * FDIM);
    unsigned short* actb = (unsigned short*)carve(sizeof(short) * (size_t)N_NODES * FDIM);
    unsigned short* e1b  = (unsigned short*)carve(sizeof(short) * (size_t)N_NODES * FDIM);
    unsigned short* Wt   = (unsigned short*)carve(sizeof(short) * 5 * 65536);
    unsigned short* Wct  = (unsigned short*)carve(sizeof(short) * 4 * 48 * 256);
    float* logits    = (float*)carve(sizeof(float) * (size_t)N_NODES * CDIM);

    bucket_hist_kernel<<<NADJ * NCHUNK, 256, 0, stream>>>(adj, bh);
    bucket_scan_kernel<<<NADJ, 256, 0, stream>>>(bh, boff);
    bucket_scatter_kernel<<<NADJ * NCHUNK, 256, 0, stream>>>(adj, boff, gbuf);
    count_kernel<<<NADJ * NBUCK, 256, 0, stream>>>(gbuf, boff, counts);
    scan_kernel<<<NADJ, 256, 0, stream>>>(counts, row_start);
    scatter2_kernel<<<NADJ * NBUCK, 256, 0, stream>>>(gbuf, boff, row_start, esrc);
    dinv_kernel<<<(NADJ * N_NODES + 255) / 256, 256, 0, stream>>>(row_start, dinv);

    convx_kernel<<<(N_NODES * FDIM / 4 + 255) / 256, 256, 0, stream>>>(x, xb);
    convw_kernel<<<(5 * 65536 + 4 * 48 * 256 + 255) / 256, 256, 0, stream>>>(
        W_convs, W_extra, W_extra2, W_cls, Wt, Wct);

    int agg_grid = (N_NODES + 3) / 4;
    int ga_grid = N_NODES / 16;                 // 3125
    int cls_grid = (N_NODES + 63) / 64;         // 782

    // jump branches: z_i = relu(agg_{i+1}(x) @ W_i + b_i) * mask[i]
    for (int i = 0; i < 3; ++i) {
        int a = i + 1;
        agg_kernel<<<agg_grid, 256, 0, stream>>>(xb, row_start + a * (N_NODES + 1),
                                                 esrc + (size_t)a * N_EDGES,
                                                 dinv + a * N_NODES, gb);
        gemm_act_mfma<<<ga_grid, 256, 0, stream>>>(gb, Wt + (size_t)i * 65536,
                                                   b_convs + i * FDIM,
                                                   nullptr, nullptr, nullptr, nullptr,
                                                   att, i, 0, actb);
        gemm_cls_mfma<<<cls_grid, 256, 0, stream>>>(actb, Wct + (size_t)i * 48 * 256,
                                                    b_cls, logits, i == 0 ? 1 : 0);
    }
    // extra branch (two GCN layers on adj[0])
    agg_kernel<<<agg_grid, 256, 0, stream>>>(xb, row_start, esrc, dinv, gb);
    gemm_act_mfma<<<ga_grid, 256, 0, stream>>>(gb, Wt + (size_t)3 * 65536, b_extra,
                                               bn1_g, bn1_b, bn1_m, bn1_v, att, 3, 1, e1b);
    agg_kernel<<<agg_grid, 256, 0, stream>>>(e1b, row_start, esrc, dinv, gb);
    gemm_act_mfma<<<ga_grid, 256, 0, stream>>>(gb, Wt + (size_t)4 * 65536, b_extra2,
                                               bn2_g, bn2_b, bn2_m, bn2_v, att, 3, 2, actb);
    gemm_cls_mfma<<<cls_grid, 256, 0, stream>>>(actb, Wct + (size_t)3 * 48 * 256,
                                                b_cls, logits, 0);

    lsm_kernel<<<(N_NODES + 3) / 4, 256, 0, stream>>>(logits, out);
}

// Round 8
// 940.386 us; speedup vs baseline: 2.3171x; 1.4669x over previous
//
#include <hip/hip_runtime.h>
#include <math.h>

#define N_NODES 50000
#define N_EDGES 800000
#define NADJ 4
#define FDIM 256
#define CDIM 40
#define BN_EPS 1e-5f
#define NBUCK 64
#define BUCK_SZ 782            // ceil(50000/64); 64*782 = 50048
#define NCHUNK 64
#define EPC (N_EDGES / NCHUNK) // 12500 edges per chunk

typedef __attribute__((ext_vector_type(8))) short short8;
typedef __attribute__((ext_vector_type(4))) float f32x4;

__device__ __forceinline__ float bf2f(unsigned short u) {
    union { unsigned int i; float f; } c; c.i = ((unsigned int)u) << 16; return c.f;
}
__device__ __forceinline__ unsigned short f2bf(float f) {
    union { float f; unsigned int i; } c; c.f = f;
    unsigned int u = c.i;
    u += 0x7fffu + ((u >> 16) & 1u);
    return (unsigned short)(u >> 16);
}

// ================================================================ CSR build
// Stage 1: per-chunk bucket histogram (LDS only, no global atomics)
__global__ __launch_bounds__(256) void bucket_hist_kernel(const int* __restrict__ adj,
                                                          int* __restrict__ bh) {
    __shared__ int cnt[NBUCK];
    int a = blockIdx.x >> 6;
    int c = blockIdx.x & (NCHUNK - 1);
    if (threadIdx.x < NBUCK) cnt[threadIdx.x] = 0;
    __syncthreads();
    const int* dsts = adj + (size_t)a * 2 * N_EDGES + N_EDGES + c * EPC;
    for (int e = threadIdx.x; e < EPC; e += 256)
        atomicAdd(&cnt[dsts[e] / BUCK_SZ], 1);
    __syncthreads();
    if (threadIdx.x < NBUCK)
        bh[(a * NBUCK + threadIdx.x) * NCHUNK + c] = cnt[threadIdx.x];
}

// Stage 2: exclusive scan of 4096 (b-major, c-minor) counts per adjacency
__global__ __launch_bounds__(256) void bucket_scan_kernel(const int* __restrict__ bh,
                                                          int* __restrict__ boff) {
    int a = blockIdx.x;
    __shared__ int wsum[4];
    __shared__ int carry;
    int lane = threadIdx.x & 63;
    int wid = threadIdx.x >> 6;
    if (threadIdx.x == 0) carry = 0;
    __syncthreads();
    for (int base = 0; base < NBUCK * NCHUNK; base += 256) {
        int j = base + threadIdx.x;
        int v = bh[a * NBUCK * NCHUNK + j];
        int x = v;
        #pragma unroll
        for (int off = 1; off < 64; off <<= 1) {
            int t = __shfl_up(x, off);
            if (lane >= off) x += t;
        }
        if (lane == 63) wsum[wid] = x;
        __syncthreads();
        if (threadIdx.x == 0) {
            int s = 0;
            #pragma unroll
            for (int w = 0; w < 4; ++w) { int t = wsum[w]; wsum[w] = s; s = t + s; }
        }
        __syncthreads();
        int inc = x + wsum[wid] + carry;
        boff[a * NBUCK * NCHUNK + j] = inc - v;   // exclusive
        __syncthreads();
        if (threadIdx.x == 255) carry = inc;
        __syncthreads();
    }
}

// Stage 3: scatter edges into bucket-grouped buffer (packed (dst<<16)|src).
// Block (a,c) writes each bucket's edges into its private contiguous subrange.
__global__ __launch_bounds__(256) void bucket_scatter_kernel(
        const int* __restrict__ adj, const int* __restrict__ boff,
        unsigned int* __restrict__ gbuf) {
    __shared__ int base[NBUCK];
    __shared__ int cnt[NBUCK];
    int a = blockIdx.x >> 6;
    int c = blockIdx.x & (NCHUNK - 1);
    if (threadIdx.x < NBUCK)
        base[threadIdx.x] = boff[(a * NBUCK + threadIdx.x) * NCHUNK + c];
    const int* dsts = adj + (size_t)a * 2 * N_EDGES + N_EDGES + c * EPC;
    const int* srcs = adj + (size_t)a * 2 * N_EDGES + c * EPC;
    unsigned int* gout = gbuf + (size_t)a * N_EDGES;
    for (int t0 = 0; t0 < EPC; t0 += 256) {
        if (threadIdx.x < NBUCK) cnt[threadIdx.x] = 0;
        __syncthreads();
        int e = t0 + threadIdx.x;
        int b = -1, r = 0; unsigned int pk = 0;
        if (e < EPC) {
            int d = dsts[e];
            int s = srcs[e];
            b = d / BUCK_SZ;
            pk = ((unsigned int)d << 16) | (unsigned int)s;
            r = atomicAdd(&cnt[b], 1);
        }
        __syncthreads();
        if (b >= 0) gout[base[b] + r] = pk;
        __syncthreads();
        if (threadIdx.x < NBUCK) base[threadIdx.x] += cnt[threadIdx.x];
        __syncthreads();
    }
}

// Stages 4-6 merged: block (a,b) counts its bucket's dsts in LDS, does an
// in-LDS exclusive scan (offset by the bucket's global edge offset bs),
// writes its row_start slice, then scatters esrc using the scanned cursors.
// Replaces the 131us serial 50k-element global scan with 256 independent
// <=782-element scans.
__global__ __launch_bounds__(256) void csr_finalize_kernel(
        const unsigned int* __restrict__ gbuf, const int* __restrict__ boff,
        int* __restrict__ row_start, unsigned short* __restrict__ esrc) {
    __shared__ int cnt[BUCK_SZ];
    __shared__ int cur[BUCK_SZ];
    __shared__ int wsum[4];
    __shared__ int carry;
    int a = blockIdx.x >> 6;
    int b = blockIdx.x & (NBUCK - 1);
    int lo = b * BUCK_SZ;
    int hi = lo + BUCK_SZ; if (hi > N_NODES) hi = N_NODES;
    int nloc = hi - lo;
    for (int i = threadIdx.x; i < BUCK_SZ; i += 256) cnt[i] = 0;
    if (threadIdx.x == 0) carry = 0;
    __syncthreads();
    int bs = boff[(a * NBUCK + b) * NCHUNK];
    int be = (b == NBUCK - 1) ? N_EDGES : boff[(a * NBUCK + b + 1) * NCHUNK];
    const unsigned int* g = gbuf + (size_t)a * N_EDGES;
    for (int p = bs + threadIdx.x; p < be; p += 256)
        atomicAdd(&cnt[(g[p] >> 16) - lo], 1);
    __syncthreads();
    // exclusive scan cnt[0..nloc) -> cur[], offset by bs
    int lane = threadIdx.x & 63;
    int wid = threadIdx.x >> 6;
    #pragma unroll
    for (int base = 0; base < BUCK_SZ; base += 256) {
        int i = base + threadIdx.x;
        int v = (i < nloc) ? cnt[i] : 0;
        int x = v;
        #pragma unroll
        for (int off = 1; off < 64; off <<= 1) {
            int t = __shfl_up(x, off);
            if (lane >= off) x += t;
        }
        if (lane == 63) wsum[wid] = x;
        __syncthreads();
        if (threadIdx.x == 0) {
            int s = 0;
            #pragma unroll
            for (int w = 0; w < 4; ++w) { int t = wsum[w]; wsum[w] = s; s = t + s; }
        }
        __syncthreads();
        int inc = x + wsum[wid] + carry;
        if (i < nloc) cur[i] = bs + inc - v;   // exclusive global offset
        __syncthreads();
        if (threadIdx.x == 255) carry = inc;
        __syncthreads();
    }
    for (int i = threadIdx.x; i < nloc; i += 256)
        row_start[a * (N_NODES + 1) + lo + i] = cur[i];
    if (b == NBUCK - 1 && threadIdx.x == 0)
        row_start[a * (N_NODES + 1) + N_NODES] = N_EDGES;
    __syncthreads();
    unsigned short* eout = esrc + (size_t)a * N_EDGES;
    for (int p = bs + threadIdx.x; p < be; p += 256) {
        unsigned int pk = g[p];
        int pos = atomicAdd(&cur[(pk >> 16) - lo], 1);
        eout[pos] = (unsigned short)(pk & 0xffffu);
    }
}

__global__ void dinv_kernel(const int* __restrict__ row_start, float* __restrict__ dinv) {
    int idx = blockIdx.x * blockDim.x + threadIdx.x;
    if (idx >= NADJ * N_NODES) return;
    int a = idx / N_NODES;
    int n = idx - a * N_NODES;
    int d = row_start[a * (N_NODES + 1) + n + 1] - row_start[a * (N_NODES + 1) + n] + 1;
    dinv[idx] = rsqrtf((float)d);
}

// ------------------------------------------------------------- conversions
__global__ void convx_kernel(const float* __restrict__ x, unsigned short* __restrict__ xb) {
    int i = blockIdx.x * blockDim.x + threadIdx.x;
    if (i >= N_NODES * FDIM / 4) return;
    float4 v = *reinterpret_cast<const float4*>(&x[(size_t)i * 4]);
    ushort4 o;
    o.x = f2bf(v.x); o.y = f2bf(v.y); o.z = f2bf(v.z); o.w = f2bf(v.w);
    *reinterpret_cast<ushort4*>(&xb[(size_t)i * 4]) = o;
}

// weights -> transposed bf16.  Wt[5][256][256]: Wt[w][n][k] = Wsrc[w][k][n]
// Wct[4][48][256]: Wct[b][c][k] = c<40 ? W_cls[(b*256+k)*40+c] : 0
__global__ void convw_kernel(const float* __restrict__ W_convs, const float* __restrict__ W_extra,
                             const float* __restrict__ W_extra2, const float* __restrict__ W_cls,
                             unsigned short* __restrict__ Wt, unsigned short* __restrict__ Wct) {
    int idx = blockIdx.x * blockDim.x + threadIdx.x;
    const int NSQ = 5 * 65536;
    if (idx < NSQ) {
        int w = idx >> 16;
        int rem = idx & 65535;
        int n = rem >> 8;
        int k = rem & 255;
        const float* src = (w < 3) ? (W_convs + (size_t)w * 65536)
                                   : ((w == 3) ? W_extra : W_extra2);
        Wt[idx] = f2bf(src[(size_t)k * 256 + n]);
    } else if (idx < NSQ + 4 * 48 * 256) {
        int rem = idx - NSQ;
        int b = rem / (48 * 256);
        int r2 = rem - b * (48 * 256);
        int c = r2 >> 8;
        int k = r2 & 255;
        float v = (c < CDIM) ? W_cls[((size_t)b * 256 + k) * CDIM + c] : 0.0f;
        Wct[rem] = f2bf(v);
    }
}

// ------------------------------------------------------------- aggregation
// one wave per node; lane handles 4 features (8B ushort4 loads).
// 4x unrolled edge loop for memory-level parallelism; dn factored out:
// g[n] = dn * ( sum dinv[s]*x[s]  +  dn*x[n] )
__global__ __launch_bounds__(256) void agg_kernel(
        const unsigned short* __restrict__ xb, const int* __restrict__ row_start,
        const unsigned short* __restrict__ esrc, const float* __restrict__ dinv,
        unsigned short* __restrict__ gout) {
    int lane = threadIdx.x & 63;
    int n = blockIdx.x * 4 + (threadIdx.x >> 6);
    if (n >= N_NODES) return;
    int beg = row_start[n];
    int end = row_start[n + 1];
    float dn = dinv[n];
    const ushort4* xr = reinterpret_cast<const ushort4*>(xb);
    ushort4 sv = xr[(size_t)n * 64 + lane];
    float a0 = 0.f, a1 = 0.f, a2 = 0.f, a3 = 0.f;
    int p = beg;
    for (; p + 4 <= end; p += 4) {
        int s0 = (int)esrc[p + 0];
        int s1 = (int)esrc[p + 1];
        int s2 = (int)esrc[p + 2];
        int s3 = (int)esrc[p + 3];
        float w0 = dinv[s0], w1 = dinv[s1], w2 = dinv[s2], w3 = dinv[s3];
        ushort4 v0 = xr[(size_t)s0 * 64 + lane];
        ushort4 v1 = xr[(size_t)s1 * 64 + lane];
        ushort4 v2 = xr[(size_t)s2 * 64 + lane];
        ushort4 v3 = xr[(size_t)s3 * 64 + lane];
        a0 += w0 * bf2f(v0.x) + w1 * bf2f(v1.x) + w2 * bf2f(v2.x) + w3 * bf2f(v3.x);
        a1 += w0 * bf2f(v0.y) + w1 * bf2f(v1.y) + w2 * bf2f(v2.y) + w3 * bf2f(v3.y);
        a2 += w0 * bf2f(v0.z) + w1 * bf2f(v1.z) + w2 * bf2f(v2.z) + w3 * bf2f(v3.z);
        a3 += w0 * bf2f(v0.w) + w1 * bf2f(v1.w) + w2 * bf2f(v2.w) + w3 * bf2f(v3.w);
    }
    for (; p < end; ++p) {
        int s = (int)esrc[p];
        float w = dinv[s];
        ushort4 v = xr[(size_t)s * 64 + lane];
        a0 += w * bf2f(v.x); a1 += w * bf2f(v.y);
        a2 += w * bf2f(v.z); a3 += w * bf2f(v.w);
    }
    ushort4 o;
    o.x = f2bf(dn * (a0 + dn * bf2f(sv.x)));
    o.y = f2bf(dn * (a1 + dn * bf2f(sv.y)));
    o.z = f2bf(dn * (a2 + dn * bf2f(sv.z)));
    o.w = f2bf(dn * (a3 + dn * bf2f(sv.w)));
    *reinterpret_cast<ushort4*>(&gout[(size_t)n * FDIM + (size_t)lane * 4]) = o;
}

// ------------------------------------------------ branch GEMM via MFMA bf16
__global__ __launch_bounds__(256) void gemm_act_mfma(
        const unsigned short* __restrict__ A, const unsigned short* __restrict__ Wt,
        const float* __restrict__ bias,
        const float* __restrict__ gamma, const float* __restrict__ beta,
        const float* __restrict__ mean, const float* __restrict__ var,
        const float* __restrict__ att, int branch, int mode,
        unsigned short* __restrict__ outb) {
    int lane = threadIdx.x & 63;
    int wv = threadIdx.x >> 6;
    int row0 = blockIdx.x * 16;          // 3125 blocks * 16 = 50000 exactly
    int n0 = wv * 64;
    int r = lane & 15;
    int g = lane >> 4;
    f32x4 acc[4] = {{0.f,0.f,0.f,0.f},{0.f,0.f,0.f,0.f},{0.f,0.f,0.f,0.f},{0.f,0.f,0.f,0.f}};
    const unsigned short* arow = A + (size_t)(row0 + r) * 256 + g * 8;
    #pragma unroll
    for (int t = 0; t < 8; ++t) {
        short8 a = *reinterpret_cast<const short8*>(arow + t * 32);
        #pragma unroll
        for (int f = 0; f < 4; ++f) {
            short8 b = *reinterpret_cast<const short8*>(
                Wt + (size_t)(n0 + f * 16 + r) * 256 + t * 32 + g * 8);
            acc[f] = __builtin_amdgcn_mfma_f32_16x16x32_bf16(a, b, acc[f], 0, 0, 0);
        }
    }
    float m4 = 1.0f;
    if (mode == 0 || mode == 2) {
        float c0 = att[0], c1 = att[1], c2 = att[2], c3 = att[3];
        float mx = fmaxf(fmaxf(c0, c1), fmaxf(c2, c3));
        float e0 = expf(c0 - mx), e1 = expf(c1 - mx), e2 = expf(c2 - mx), e3 = expf(c3 - mx);
        float s = e0 + e1 + e2 + e3;
        float sel = (branch == 0) ? e0 : (branch == 1) ? e1 : (branch == 2) ? e2 : e3;
        m4 = sel / s;
    }
    #pragma unroll
    for (int f = 0; f < 4; ++f) {
        int col = n0 + f * 16 + r;
        float bi = bias[col];
        float mu = 0.f, rs = 1.f, ga = 1.f, be = 0.f;
        if (mode >= 1) {
            mu = mean[col]; rs = rsqrtf(var[col] + BN_EPS); ga = gamma[col]; be = beta[col];
        }
        #pragma unroll
        for (int j = 0; j < 4; ++j) {
            int row = row0 + g * 4 + j;
            float y = acc[f][j] + bi;
            if (mode >= 1) y = (y - mu) * rs * ga + be;
            y = fmaxf(y, 0.0f) * m4;
            outb[(size_t)row * 256 + col] = f2bf(y);
        }
    }
}

// -------------------------------------- classifier partial GEMM into logits
__global__ __launch_bounds__(256) void gemm_cls_mfma(
        const unsigned short* __restrict__ A, const unsigned short* __restrict__ Wct,
        const float* __restrict__ bcls, float* __restrict__ logits, int first) {
    int lane = threadIdx.x & 63;
    int wv = threadIdx.x >> 6;
    int row0 = blockIdx.x * 64 + wv * 16;
    int r = lane & 15;
    int g = lane >> 4;
    f32x4 acc[3] = {{0.f,0.f,0.f,0.f},{0.f,0.f,0.f,0.f},{0.f,0.f,0.f,0.f}};
    int ar = row0 + r; if (ar > N_NODES - 1) ar = N_NODES - 1;
    const unsigned short* arow = A + (size_t)ar * 256 + g * 8;
    #pragma unroll
    for (int t = 0; t < 8; ++t) {
        short8 a = *reinterpret_cast<const short8*>(arow + t * 32);
        #pragma unroll
        for (int f = 0; f < 3; ++f) {
            short8 b = *reinterpret_cast<const short8*>(
                Wct + (size_t)(f * 16 + r) * 256 + t * 32 + g * 8);
            acc[f] = __builtin_amdgcn_mfma_f32_16x16x32_bf16(a, b, acc[f], 0, 0, 0);
        }
    }
    #pragma unroll
    for (int f = 0; f < 3; ++f) {
        int col = f * 16 + r;
        if (col >= CDIM) continue;
        float bi = bcls[col];
        #pragma unroll
        for (int j = 0; j < 4; ++j) {
            int row = row0 + g * 4 + j;
            if (row >= N_NODES) continue;
            float v = acc[f][j];
            if (first) logits[(size_t)row * CDIM + col] = v + bi;
            else       logits[(size_t)row * CDIM + col] += v;
        }
    }
}

// ----------------------------------------------------------- log_softmax
__global__ void lsm_kernel(const float* __restrict__ logits, float* __restrict__ out) {
    int n = blockIdx.x * 4 + (threadIdx.x >> 6);
    int lane = threadIdx.x & 63;
    if (blockIdx.x == 0 && threadIdx.x == 0)
        out[(size_t)N_NODES * CDIM] = 0.0f;   // trailing scalar output
    if (n >= N_NODES) return;
    float v = (lane < CDIM) ? logits[(size_t)n * CDIM + lane] : -INFINITY;
    float m = v;
    #pragma unroll
    for (int off = 32; off >= 1; off >>= 1) m = fmaxf(m, __shfl_xor(m, off));
    float ex = (lane < CDIM) ? expf(v - m) : 0.0f;
    float s = ex;
    #pragma unroll
    for (int off = 32; off >= 1; off >>= 1) s += __shfl_xor(s, off);
    float ls = logf(s) + m;
    if (lane < CDIM) out[(size_t)n * CDIM + lane] = v - ls;
}

// ------------------------------------------------------------------ launch
extern "C" void kernel_launch(void* const* d_in, const int* in_sizes, int n_in,
                              void* d_out, int out_size, void* d_ws, size_t ws_size,
                              hipStream_t stream) {
    const float* x        = (const float*)d_in[0];
    const int*   adj      = (const int*)d_in[1];
    const float* W_convs  = (const float*)d_in[2];
    const float* b_convs  = (const float*)d_in[3];
    const float* W_extra  = (const float*)d_in[4];
    const float* b_extra  = (const float*)d_in[5];
    const float* bn1_g    = (const float*)d_in[6];
    const float* bn1_b    = (const float*)d_in[7];
    const float* bn1_m    = (const float*)d_in[8];
    const float* bn1_v    = (const float*)d_in[9];
    const float* W_extra2 = (const float*)d_in[10];
    const float* b_extra2 = (const float*)d_in[11];
    const float* bn2_g    = (const float*)d_in[12];
    const float* bn2_b    = (const float*)d_in[13];
    const float* bn2_m    = (const float*)d_in[14];
    const float* bn2_v    = (const float*)d_in[15];
    const float* att      = (const float*)d_in[16];
    const float* W_cls    = (const float*)d_in[17];
    const float* b_cls    = (const float*)d_in[18];
    float* out = (float*)d_out;

    char* base = (char*)d_ws;
    size_t off = 0;
    auto carve = [&](size_t bytes) -> char* {
        char* p = base + off;
        off = (off + bytes + 255) & ~(size_t)255;
        return p;
    };
    int*   row_start = (int*)carve(sizeof(int) * NADJ * (N_NODES + 1));
    int*   bh        = (int*)carve(sizeof(int) * NADJ * NBUCK * NCHUNK);
    int*   boff      = (int*)carve(sizeof(int) * NADJ * NBUCK * NCHUNK);
    unsigned int* gbuf = (unsigned int*)carve(sizeof(int) * (size_t)NADJ * N_EDGES);
    unsigned short* esrc = (unsigned short*)carve(sizeof(short) * (size_t)NADJ * N_EDGES);
    float* dinv      = (float*)carve(sizeof(float) * NADJ * N_NODES);
    unsigned short* xb   = (unsigned short*)carve(sizeof(short) * (size_t)N_NODES * FDIM);
    unsigned short* gb   = (unsigned short*)carve(sizeof(short) * (size_t)N_NODES * FDIM);
    unsigned short* actb = (unsigned short*)carve(sizeof(short) * (size_t)N_NODES * FDIM);
    unsigned short* e1b  = (unsigned short*)carve(sizeof(short) * (size_t)N_NODES * FDIM);
    unsigned short* Wt   = (unsigned short*)carve(sizeof(short) * 5 * 65536);
    unsigned short* Wct  = (unsigned short*)carve(sizeof(short) * 4 * 48 * 256);
    float* logits    = (float*)carve(sizeof(float) * (size_t)N_NODES * CDIM);

    bucket_hist_kernel<<<NADJ * NCHUNK, 256, 0, stream>>>(adj, bh);
    bucket_scan_kernel<<<NADJ, 256, 0, stream>>>(bh, boff);
    bucket_scatter_kernel<<<NADJ * NCHUNK, 256, 0, stream>>>(adj, boff, gbuf);
    csr_finalize_kernel<<<NADJ * NBUCK, 256, 0, stream>>>(gbuf, boff, row_start, esrc);
    dinv_kernel<<<(NADJ * N_NODES + 255) / 256, 256, 0, stream>>>(row_start, dinv);

    convx_kernel<<<(N_NODES * FDIM / 4 + 255) / 256, 256, 0, stream>>>(x, xb);
    convw_kernel<<<(5 * 65536 + 4 * 48 * 256 + 255) / 256, 256, 0, stream>>>(
        W_convs, W_extra, W_extra2, W_cls, Wt, Wct);

    int agg_grid = (N_NODES + 3) / 4;
    int ga_grid = N_NODES / 16;                 // 3125
    int cls_grid = (N_NODES + 63) / 64;         // 782

    // jump branches: z_i = relu(agg_{i+1}(x) @ W_i + b_i) * mask[i]
    for (int i = 0; i < 3; ++i) {
        int a = i + 1;
        agg_kernel<<<agg_grid, 256, 0, stream>>>(xb, row_start + a * (N_NODES + 1),
                                                 esrc + (size_t)a * N_EDGES,
                                                 dinv + a * N_NODES, gb);
        gemm_act_mfma<<<ga_grid, 256, 0, stream>>>(gb, Wt + (size_t)i * 65536,
                                                   b_convs + i * FDIM,
                                                   nullptr, nullptr, nullptr, nullptr,
                                                   att, i, 0, actb);
        gemm_cls_mfma<<<cls_grid, 256, 0, stream>>>(actb, Wct + (size_t)i * 48 * 256,
                                                    b_cls, logits, i == 0 ? 1 : 0);
    }
    // extra branch (two GCN layers on adj[0])
    agg_kernel<<<agg_grid, 256, 0, stream>>>(xb, row_start, esrc, dinv, gb);
    gemm_act_mfma<<<ga_grid, 256, 0, stream>>>(gb, Wt + (size_t)3 * 65536, b_extra,
                                               bn1_g, bn1_b, bn1_m, bn1_v, att, 3, 1, e1b);
    agg_kernel<<<agg_grid, 256, 0, stream>>>(e1b, row_start, esrc, dinv, gb);
    gemm_act_mfma<<<ga_grid, 256, 0, stream>>>(gb, Wt + (size_t)4 * 65536, b_extra2,
                                               bn2_g, bn2_b, bn2_m, bn2_v, att, 3, 2, actb);
    gemm_cls_mfma<<<cls_grid, 256, 0, stream>>>(actb, Wct + (size_t)3 * 48 * 256,
                                                b_cls, logits, 0);

    lsm_kernel<<<(N_NODES + 3) / 4, 256, 0, stream>>>(logits, out);
}

// Round 9
// 881.486 us; speedup vs baseline: 2.4719x; 1.0668x over previous
//
#include <hip/hip_runtime.h>
#include <math.h>

#define N_NODES 50000
#define N_EDGES 800000
#define NADJ 4
#define FDIM 256
#define CDIM 40
#define BN_EPS 1e-5f
#define NBUCK 64
#define BUCK_SZ 782            // ceil(50000/64); 64*782 = 50048
#define NCHUNK 64
#define EPC (N_EDGES / NCHUNK) // 12500 edges per chunk

typedef __attribute__((ext_vector_type(8))) short short8;
typedef __attribute__((ext_vector_type(4))) float f32x4;

__device__ __forceinline__ float bf2f(unsigned short u) {
    union { unsigned int i; float f; } c; c.i = ((unsigned int)u) << 16; return c.f;
}
__device__ __forceinline__ unsigned short f2bf(float f) {
    union { float f; unsigned int i; } c; c.f = f;
    unsigned int u = c.i;
    u += 0x7fffu + ((u >> 16) & 1u);
    return (unsigned short)(u >> 16);
}

// ================================================================ CSR build
__global__ __launch_bounds__(256) void bucket_hist_kernel(const int* __restrict__ adj,
                                                          int* __restrict__ bh) {
    __shared__ int cnt[NBUCK];
    int a = blockIdx.x >> 6;
    int c = blockIdx.x & (NCHUNK - 1);
    if (threadIdx.x < NBUCK) cnt[threadIdx.x] = 0;
    __syncthreads();
    const int* dsts = adj + (size_t)a * 2 * N_EDGES + N_EDGES + c * EPC;
    for (int e = threadIdx.x; e < EPC; e += 256)
        atomicAdd(&cnt[dsts[e] / BUCK_SZ], 1);
    __syncthreads();
    if (threadIdx.x < NBUCK)
        bh[(a * NBUCK + threadIdx.x) * NCHUNK + c] = cnt[threadIdx.x];
}

__global__ __launch_bounds__(256) void bucket_scan_kernel(const int* __restrict__ bh,
                                                          int* __restrict__ boff) {
    int a = blockIdx.x;
    __shared__ int wsum[4];
    __shared__ int carry;
    int lane = threadIdx.x & 63;
    int wid = threadIdx.x >> 6;
    if (threadIdx.x == 0) carry = 0;
    __syncthreads();
    for (int base = 0; base < NBUCK * NCHUNK; base += 256) {
        int j = base + threadIdx.x;
        int v = bh[a * NBUCK * NCHUNK + j];
        int x = v;
        #pragma unroll
        for (int off = 1; off < 64; off <<= 1) {
            int t = __shfl_up(x, off);
            if (lane >= off) x += t;
        }
        if (lane == 63) wsum[wid] = x;
        __syncthreads();
        if (threadIdx.x == 0) {
            int s = 0;
            #pragma unroll
            for (int w = 0; w < 4; ++w) { int t = wsum[w]; wsum[w] = s; s = t + s; }
        }
        __syncthreads();
        int inc = x + wsum[wid] + carry;
        boff[a * NBUCK * NCHUNK + j] = inc - v;   // exclusive
        __syncthreads();
        if (threadIdx.x == 255) carry = inc;
        __syncthreads();
    }
}

__global__ __launch_bounds__(256) void bucket_scatter_kernel(
        const int* __restrict__ adj, const int* __restrict__ boff,
        unsigned int* __restrict__ gbuf) {
    __shared__ int base[NBUCK];
    __shared__ int cnt[NBUCK];
    int a = blockIdx.x >> 6;
    int c = blockIdx.x & (NCHUNK - 1);
    if (threadIdx.x < NBUCK)
        base[threadIdx.x] = boff[(a * NBUCK + threadIdx.x) * NCHUNK + c];
    const int* dsts = adj + (size_t)a * 2 * N_EDGES + N_EDGES + c * EPC;
    const int* srcs = adj + (size_t)a * 2 * N_EDGES + c * EPC;
    unsigned int* gout = gbuf + (size_t)a * N_EDGES;
    for (int t0 = 0; t0 < EPC; t0 += 256) {
        if (threadIdx.x < NBUCK) cnt[threadIdx.x] = 0;
        __syncthreads();
        int e = t0 + threadIdx.x;
        int b = -1, r = 0; unsigned int pk = 0;
        if (e < EPC) {
            int d = dsts[e];
            int s = srcs[e];
            b = d / BUCK_SZ;
            pk = ((unsigned int)d << 16) | (unsigned int)s;
            r = atomicAdd(&cnt[b], 1);
        }
        __syncthreads();
        if (b >= 0) gout[base[b] + r] = pk;
        __syncthreads();
        if (threadIdx.x < NBUCK) base[threadIdx.x] += cnt[threadIdx.x];
        __syncthreads();
    }
}

// Stages 4-6 merged: per-bucket count + in-LDS scan + scatter
__global__ __launch_bounds__(256) void csr_finalize_kernel(
        const unsigned int* __restrict__ gbuf, const int* __restrict__ boff,
        int* __restrict__ row_start, unsigned short* __restrict__ esrc) {
    __shared__ int cnt[BUCK_SZ];
    __shared__ int cur[BUCK_SZ];
    __shared__ int wsum[4];
    __shared__ int carry;
    int a = blockIdx.x >> 6;
    int b = blockIdx.x & (NBUCK - 1);
    int lo = b * BUCK_SZ;
    int hi = lo + BUCK_SZ; if (hi > N_NODES) hi = N_NODES;
    int nloc = hi - lo;
    for (int i = threadIdx.x; i < BUCK_SZ; i += 256) cnt[i] = 0;
    if (threadIdx.x == 0) carry = 0;
    __syncthreads();
    int bs = boff[(a * NBUCK + b) * NCHUNK];
    int be = (b == NBUCK - 1) ? N_EDGES : boff[(a * NBUCK + b + 1) * NCHUNK];
    const unsigned int* g = gbuf + (size_t)a * N_EDGES;
    for (int p = bs + threadIdx.x; p < be; p += 256)
        atomicAdd(&cnt[(g[p] >> 16) - lo], 1);
    __syncthreads();
    int lane = threadIdx.x & 63;
    int wid = threadIdx.x >> 6;
    #pragma unroll
    for (int base = 0; base < BUCK_SZ; base += 256) {
        int i = base + threadIdx.x;
        int v = (i < nloc) ? cnt[i] : 0;
        int x = v;
        #pragma unroll
        for (int off = 1; off < 64; off <<= 1) {
            int t = __shfl_up(x, off);
            if (lane >= off) x += t;
        }
        if (lane == 63) wsum[wid] = x;
        __syncthreads();
        if (threadIdx.x == 0) {
            int s = 0;
            #pragma unroll
            for (int w = 0; w < 4; ++w) { int t = wsum[w]; wsum[w] = s; s = t + s; }
        }
        __syncthreads();
        int inc = x + wsum[wid] + carry;
        if (i < nloc) cur[i] = bs + inc - v;   // exclusive global offset
        __syncthreads();
        if (threadIdx.x == 255) carry = inc;
        __syncthreads();
    }
    for (int i = threadIdx.x; i < nloc; i += 256)
        row_start[a * (N_NODES + 1) + lo + i] = cur[i];
    if (b == NBUCK - 1 && threadIdx.x == 0)
        row_start[a * (N_NODES + 1) + N_NODES] = N_EDGES;
    __syncthreads();
    unsigned short* eout = esrc + (size_t)a * N_EDGES;
    for (int p = bs + threadIdx.x; p < be; p += 256) {
        unsigned int pk = g[p];
        int pos = atomicAdd(&cur[(pk >> 16) - lo], 1);
        eout[pos] = (unsigned short)(pk & 0xffffu);
    }
}

__global__ void dinv_kernel(const int* __restrict__ row_start, float* __restrict__ dinv) {
    int idx = blockIdx.x * blockDim.x + threadIdx.x;
    if (idx >= NADJ * N_NODES) return;
    int a = idx / N_NODES;
    int n = idx - a * N_NODES;
    int d = row_start[a * (N_NODES + 1) + n + 1] - row_start[a * (N_NODES + 1) + n] + 1;
    dinv[idx] = rsqrtf((float)d);
}

// ------------------------------------------------------------- conversions
__global__ void convx_kernel(const float* __restrict__ x, unsigned short* __restrict__ xb) {
    int i = blockIdx.x * blockDim.x + threadIdx.x;
    if (i >= N_NODES * FDIM / 4) return;
    float4 v = *reinterpret_cast<const float4*>(&x[(size_t)i * 4]);
    ushort4 o;
    o.x = f2bf(v.x); o.y = f2bf(v.y); o.z = f2bf(v.z); o.w = f2bf(v.w);
    *reinterpret_cast<ushort4*>(&xb[(size_t)i * 4]) = o;
}

__global__ void convw_kernel(const float* __restrict__ W_convs, const float* __restrict__ W_extra,
                             const float* __restrict__ W_extra2, const float* __restrict__ W_cls,
                             unsigned short* __restrict__ Wt, unsigned short* __restrict__ Wct) {
    int idx = blockIdx.x * blockDim.x + threadIdx.x;
    const int NSQ = 5 * 65536;
    if (idx < NSQ) {
        int w = idx >> 16;
        int rem = idx & 65535;
        int n = rem >> 8;
        int k = rem & 255;
        const float* src = (w < 3) ? (W_convs + (size_t)w * 65536)
                                   : ((w == 3) ? W_extra : W_extra2);
        Wt[idx] = f2bf(src[(size_t)k * 256 + n]);
    } else if (idx < NSQ + 4 * 48 * 256) {
        int rem = idx - NSQ;
        int b = rem / (48 * 256);
        int r2 = rem - b * (48 * 256);
        int c = r2 >> 8;
        int k = r2 & 255;
        float v = (c < CDIM) ? W_cls[((size_t)b * 256 + k) * CDIM + c] : 0.0f;
        Wct[rem] = f2bf(v);
    }
}

// ------------------------------------------------------------- aggregation
__global__ __launch_bounds__(256) void agg_kernel(
        const unsigned short* __restrict__ xb, const int* __restrict__ row_start,
        const unsigned short* __restrict__ esrc, const float* __restrict__ dinv,
        unsigned short* __restrict__ gout) {
    int lane = threadIdx.x & 63;
    int n = blockIdx.x * 4 + (threadIdx.x >> 6);
    if (n >= N_NODES) return;
    int beg = row_start[n];
    int end = row_start[n + 1];
    float dn = dinv[n];
    const ushort4* xr = reinterpret_cast<const ushort4*>(xb);
    ushort4 sv = xr[(size_t)n * 64 + lane];
    float a0 = 0.f, a1 = 0.f, a2 = 0.f, a3 = 0.f;
    int p = beg;
    for (; p + 4 <= end; p += 4) {
        int s0 = (int)esrc[p + 0];
        int s1 = (int)esrc[p + 1];
        int s2 = (int)esrc[p + 2];
        int s3 = (int)esrc[p + 3];
        float w0 = dinv[s0], w1 = dinv[s1], w2 = dinv[s2], w3 = dinv[s3];
        ushort4 v0 = xr[(size_t)s0 * 64 + lane];
        ushort4 v1 = xr[(size_t)s1 * 64 + lane];
        ushort4 v2 = xr[(size_t)s2 * 64 + lane];
        ushort4 v3 = xr[(size_t)s3 * 64 + lane];
        a0 += w0 * bf2f(v0.x) + w1 * bf2f(v1.x) + w2 * bf2f(v2.x) + w3 * bf2f(v3.x);
        a1 += w0 * bf2f(v0.y) + w1 * bf2f(v1.y) + w2 * bf2f(v2.y) + w3 * bf2f(v3.y);
        a2 += w0 * bf2f(v0.z) + w1 * bf2f(v1.z) + w2 * bf2f(v2.z) + w3 * bf2f(v3.z);
        a3 += w0 * bf2f(v0.w) + w1 * bf2f(v1.w) + w2 * bf2f(v2.w) + w3 * bf2f(v3.w);
    }
    for (; p < end; ++p) {
        int s = (int)esrc[p];
        float w = dinv[s];
        ushort4 v = xr[(size_t)s * 64 + lane];
        a0 += w * bf2f(v.x); a1 += w * bf2f(v.y);
        a2 += w * bf2f(v.z); a3 += w * bf2f(v.w);
    }
    ushort4 o;
    o.x = f2bf(dn * (a0 + dn * bf2f(sv.x)));
    o.y = f2bf(dn * (a1 + dn * bf2f(sv.y)));
    o.z = f2bf(dn * (a2 + dn * bf2f(sv.z)));
    o.w = f2bf(dn * (a3 + dn * bf2f(sv.w)));
    *reinterpret_cast<ushort4*>(&gout[(size_t)n * FDIM + (size_t)lane * 4]) = o;
}

// ------------------------------------------------ branch GEMM via MFMA bf16
// 64-row block tile: wave wv -> cols [wv*64, +64) x rows [row0, +64).
// Per k-step: 4 A-frag + 4 B-frag loads feed 16 MFMAs (2:1 MFMA:load).
__global__ __launch_bounds__(256) void gemm_act_mfma(
        const unsigned short* __restrict__ A, const unsigned short* __restrict__ Wt,
        const float* __restrict__ bias,
        const float* __restrict__ gamma, const float* __restrict__ beta,
        const float* __restrict__ mean, const float* __restrict__ var,
        const float* __restrict__ att, int branch, int mode,
        unsigned short* __restrict__ outb) {
    int lane = threadIdx.x & 63;
    int wv = threadIdx.x >> 6;
    int row0 = blockIdx.x * 64;
    int n0 = wv * 64;
    int r = lane & 15;
    int g = lane >> 4;
    f32x4 acc[4][4] = {};
    #pragma unroll
    for (int t = 0; t < 8; ++t) {
        short8 a[4];
        #pragma unroll
        for (int m = 0; m < 4; ++m) {
            int row = row0 + m * 16 + r;
            if (row > N_NODES - 1) row = N_NODES - 1;
            a[m] = *reinterpret_cast<const short8*>(A + (size_t)row * 256 + t * 32 + g * 8);
        }
        #pragma unroll
        for (int f = 0; f < 4; ++f) {
            short8 b = *reinterpret_cast<const short8*>(
                Wt + (size_t)(n0 + f * 16 + r) * 256 + t * 32 + g * 8);
            #pragma unroll
            for (int m = 0; m < 4; ++m)
                acc[m][f] = __builtin_amdgcn_mfma_f32_16x16x32_bf16(a[m], b, acc[m][f], 0, 0, 0);
        }
    }
    float m4 = 1.0f;
    if (mode == 0 || mode == 2) {
        float c0 = att[0], c1 = att[1], c2 = att[2], c3 = att[3];
        float mx = fmaxf(fmaxf(c0, c1), fmaxf(c2, c3));
        float e0 = expf(c0 - mx), e1 = expf(c1 - mx), e2 = expf(c2 - mx), e3 = expf(c3 - mx);
        float s = e0 + e1 + e2 + e3;
        float sel = (branch == 0) ? e0 : (branch == 1) ? e1 : (branch == 2) ? e2 : e3;
        m4 = sel / s;
    }
    #pragma unroll
    for (int f = 0; f < 4; ++f) {
        int col = n0 + f * 16 + r;
        float bi = bias[col];
        float mu = 0.f, rs = 1.f, ga = 1.f, be = 0.f;
        if (mode >= 1) {
            mu = mean[col]; rs = rsqrtf(var[col] + BN_EPS); ga = gamma[col]; be = beta[col];
        }
        #pragma unroll
        for (int m = 0; m < 4; ++m) {
            #pragma unroll
            for (int j = 0; j < 4; ++j) {
                int row = row0 + m * 16 + g * 4 + j;
                if (row >= N_NODES) continue;
                float y = acc[m][f][j] + bi;
                if (mode >= 1) y = (y - mu) * rs * ga + be;
                y = fmaxf(y, 0.0f) * m4;
                outb[(size_t)row * 256 + col] = f2bf(y);
            }
        }
    }
}

// -------------------------------------- classifier partial GEMM into logits
// 256-row block; wave wv -> rows [blk*256 + wv*64, +64), cols 0..47.
__global__ __launch_bounds__(256) void gemm_cls_mfma(
        const unsigned short* __restrict__ A, const unsigned short* __restrict__ Wct,
        const float* __restrict__ bcls, float* __restrict__ logits, int first) {
    int lane = threadIdx.x & 63;
    int wv = threadIdx.x >> 6;
    int row0 = blockIdx.x * 256 + wv * 64;
    int r = lane & 15;
    int g = lane >> 4;
    f32x4 acc[4][3] = {};
    #pragma unroll
    for (int t = 0; t < 8; ++t) {
        short8 a[4];
        #pragma unroll
        for (int m = 0; m < 4; ++m) {
            int row = row0 + m * 16 + r;
            if (row > N_NODES - 1) row = N_NODES - 1;
            a[m] = *reinterpret_cast<const short8*>(A + (size_t)row * 256 + t * 32 + g * 8);
        }
        #pragma unroll
        for (int f = 0; f < 3; ++f) {
            short8 b = *reinterpret_cast<const short8*>(
                Wct + (size_t)(f * 16 + r) * 256 + t * 32 + g * 8);
            #pragma unroll
            for (int m = 0; m < 4; ++m)
                acc[m][f] = __builtin_amdgcn_mfma_f32_16x16x32_bf16(a[m], b, acc[m][f], 0, 0, 0);
        }
    }
    #pragma unroll
    for (int f = 0; f < 3; ++f) {
        int col = f * 16 + r;
        if (col >= CDIM) continue;
        float bi = bcls[col];
        #pragma unroll
        for (int m = 0; m < 4; ++m) {
            #pragma unroll
            for (int j = 0; j < 4; ++j) {
                int row = row0 + m * 16 + g * 4 + j;
                if (row >= N_NODES) continue;
                float v = acc[m][f][j];
                if (first) logits[(size_t)row * CDIM + col] = v + bi;
                else       logits[(size_t)row * CDIM + col] += v;
            }
        }
    }
}

// ----------------------------------------------------------- log_softmax
__global__ void lsm_kernel(const float* __restrict__ logits, float* __restrict__ out) {
    int n = blockIdx.x * 4 + (threadIdx.x >> 6);
    int lane = threadIdx.x & 63;
    if (blockIdx.x == 0 && threadIdx.x == 0)
        out[(size_t)N_NODES * CDIM] = 0.0f;   // trailing scalar output
    if (n >= N_NODES) return;
    float v = (lane < CDIM) ? logits[(size_t)n * CDIM + lane] : -INFINITY;
    float m = v;
    #pragma unroll
    for (int off = 32; off >= 1; off >>= 1) m = fmaxf(m, __shfl_xor(m, off));
    float ex = (lane < CDIM) ? expf(v - m) : 0.0f;
    float s = ex;
    #pragma unroll
    for (int off = 32; off >= 1; off >>= 1) s += __shfl_xor(s, off);
    float ls = logf(s) + m;
    if (lane < CDIM) out[(size_t)n * CDIM + lane] = v - ls;
}

// ------------------------------------------------------------------ launch
extern "C" void kernel_launch(void* const* d_in, const int* in_sizes, int n_in,
                              void* d_out, int out_size, void* d_ws, size_t ws_size,
                              hipStream_t stream) {
    const float* x        = (const float*)d_in[0];
    const int*   adj      = (const int*)d_in[1];
    const float* W_convs  = (const float*)d_in[2];
    const float* b_convs  = (const float*)d_in[3];
    const float* W_extra  = (const float*)d_in[4];
    const float* b_extra  = (const float*)d_in[5];
    const float* bn1_g    = (const float*)d_in[6];
    const float* bn1_b    = (const float*)d_in[7];
    const float* bn1_m    = (const float*)d_in[8];
    const float* bn1_v    = (const float*)d_in[9];
    const float* W_extra2 = (const float*)d_in[10];
    const float* b_extra2 = (const float*)d_in[11];
    const float* bn2_g    = (const float*)d_in[12];
    const float* bn2_b    = (const float*)d_in[13];
    const float* bn2_m    = (const float*)d_in[14];
    const float* bn2_v    = (const float*)d_in[15];
    const float* att      = (const float*)d_in[16];
    const float* W_cls    = (const float*)d_in[17];
    const float* b_cls    = (const float*)d_in[18];
    float* out = (float*)d_out;

    char* base = (char*)d_ws;
    size_t off = 0;
    auto carve = [&](size_t bytes) -> char* {
        char* p = base + off;
        off = (off + bytes + 255) & ~(size_t)255;
        return p;
    };
    int*   row_start = (int*)carve(sizeof(int) * NADJ * (N_NODES + 1));
    int*   bh        = (int*)carve(sizeof(int) * NADJ * NBUCK * NCHUNK);
    int*   boff      = (int*)carve(sizeof(int) * NADJ * NBUCK * NCHUNK);
    unsigned int* gbuf = (unsigned int*)carve(sizeof(int) * (size_t)NADJ * N_EDGES);
    unsigned short* esrc = (unsigned short*)carve(sizeof(short) * (size_t)NADJ * N_EDGES);
    float* dinv      = (float*)carve(sizeof(float) * NADJ * N_NODES);
    unsigned short* xb   = (unsigned short*)carve(sizeof(short) * (size_t)N_NODES * FDIM);
    unsigned short* gb   = (unsigned short*)carve(sizeof(short) * (size_t)N_NODES * FDIM);
    unsigned short* actb = (unsigned short*)carve(sizeof(short) * (size_t)N_NODES * FDIM);
    unsigned short* e1b  = (unsigned short*)carve(sizeof(short) * (size_t)N_NODES * FDIM);
    unsigned short* Wt   = (unsigned short*)carve(sizeof(short) * 5 * 65536);
    unsigned short* Wct  = (unsigned short*)carve(sizeof(short) * 4 * 48 * 256);
    float* logits    = (float*)carve(sizeof(float) * (size_t)N_NODES * CDIM);

    bucket_hist_kernel<<<NADJ * NCHUNK, 256, 0, stream>>>(adj, bh);
    bucket_scan_kernel<<<NADJ, 256, 0, stream>>>(bh, boff);
    bucket_scatter_kernel<<<NADJ * NCHUNK, 256, 0, stream>>>(adj, boff, gbuf);
    csr_finalize_kernel<<<NADJ * NBUCK, 256, 0, stream>>>(gbuf, boff, row_start, esrc);
    dinv_kernel<<<(NADJ * N_NODES + 255) / 256, 256, 0, stream>>>(row_start, dinv);

    convx_kernel<<<(N_NODES * FDIM / 4 + 255) / 256, 256, 0, stream>>>(x, xb);
    convw_kernel<<<(5 * 65536 + 4 * 48 * 256 + 255) / 256, 256, 0, stream>>>(
        W_convs, W_extra, W_extra2, W_cls, Wt, Wct);

    int agg_grid = (N_NODES + 3) / 4;
    int ga_grid = (N_NODES + 63) / 64;          // 782
    int cls_grid = (N_NODES + 255) / 256;       // 196

    // jump branches: z_i = relu(agg_{i+1}(x) @ W_i + b_i) * mask[i]
    for (int i = 0; i < 3; ++i) {
        int a = i + 1;
        agg_kernel<<<agg_grid, 256, 0, stream>>>(xb, row_start + a * (N_NODES + 1),
                                                 esrc + (size_t)a * N_EDGES,
                                                 dinv + a * N_NODES, gb);
        gemm_act_mfma<<<ga_grid, 256, 0, stream>>>(gb, Wt + (size_t)i * 65536,
                                                   b_convs + i * FDIM,
                                                   nullptr, nullptr, nullptr, nullptr,
                                                   att, i, 0, actb);
        gemm_cls_mfma<<<cls_grid, 256, 0, stream>>>(actb, Wct + (size_t)i * 48 * 256,
                                                    b_cls, logits, i == 0 ? 1 : 0);
    }
    // extra branch (two GCN layers on adj[0])
    agg_kernel<<<agg_grid, 256, 0, stream>>>(xb, row_start, esrc, dinv, gb);
    gemm_act_mfma<<<ga_grid, 256, 0, stream>>>(gb, Wt + (size_t)3 * 65536, b_extra,
                                               bn1_g, bn1_b, bn1_m, bn1_v, att, 3, 1, e1b);
    agg_kernel<<<agg_grid, 256, 0, stream>>>(e1b, row_start, esrc, dinv, gb);
    gemm_act_mfma<<<ga_grid, 256, 0, stream>>>(gb, Wt + (size_t)4 * 65536, b_extra2,
                                               bn2_g, bn2_b, bn2_m, bn2_v, att, 3, 2, actb);
    gemm_cls_mfma<<<cls_grid, 256, 0, stream>>>(actb, Wct + (size_t)3 * 48 * 256,
                                                b_cls, logits, 0);

    lsm_kernel<<<(N_NODES + 3) / 4, 256, 0, stream>>>(logits, out);
}